// Round 1
// baseline (5102.271 us; speedup 1.0000x reference)
//
#include <hip/hip_runtime.h>

#define NN 400000
#define NE 800000
#define NG 16384

static inline int cdiv(int a, int b) { return (a + b - 1) / b; }

__global__ __launch_bounds__(256) void fill_kernel(float* __restrict__ p, float v, int n) {
    int i = blockIdx.x * blockDim.x + threadIdx.x;
    if (i < n) p[i] = v;
}

__global__ __launch_bounds__(256) void deg_count_kernel(const int* __restrict__ dst,
                                                        float* __restrict__ deg, int E) {
    int e = blockIdx.x * blockDim.x + threadIdx.x;
    if (e < E) atomicAdd(&deg[dst[e]], 1.0f);
}

__global__ __launch_bounds__(256) void rsqrt_kernel(float* __restrict__ deg, int n) {
    int i = blockIdx.x * blockDim.x + threadIdx.x;
    if (i < n) deg[i] = rsqrtf(deg[i]);
}

// C[M,N] = act(A)[M,K] @ B[K,N]  (+bias, relu if EPI)
// BM=64, BN=64, BK=16, 256 threads, 4x4 per thread.
template <bool RELU_A, bool EPI>
__global__ __launch_bounds__(256) void gemm_kernel(const float* __restrict__ A,
                                                   const float* __restrict__ B,
                                                   const float* __restrict__ bias,
                                                   float* __restrict__ C,
                                                   int M, int N, int K) {
    const int BM = 64, BN = 64, BK = 16;
    __shared__ float As[BK][BM + 4];
    __shared__ float Bs[BK][BN + 4];

    const int tid = threadIdx.x;
    const int bm = blockIdx.x * BM;
    const int bn = blockIdx.y * BN;
    const int tx = tid & 15;       // 0..15 -> col group
    const int ty = tid >> 4;       // 0..15 -> row group

    const int arow = tid >> 2;          // 0..63
    const int acol = (tid & 3) * 4;     // 0,4,8,12
    const int brow = tid >> 4;          // 0..15
    const int bcol = (tid & 15) * 4;    // 0..60

    float acc[4][4] = {};

    for (int k0 = 0; k0 < K; k0 += BK) {
        // A tile (scalar loads: K may be 78, rows not 16B aligned)
        {
            const float* ap = A + (size_t)(bm + arow) * K;
#pragma unroll
            for (int j = 0; j < 4; ++j) {
                int kk = k0 + acol + j;
                float v = (kk < K) ? ap[kk] : 0.0f;
                if (RELU_A) v = fmaxf(v, 0.0f);
                As[acol + j][arow] = v;
            }
        }
        // B tile (float4)
        {
            int kk = k0 + brow;
            float4 v = make_float4(0.f, 0.f, 0.f, 0.f);
            if (kk < K) v = *reinterpret_cast<const float4*>(B + (size_t)kk * N + bn + bcol);
            *reinterpret_cast<float4*>(&Bs[brow][bcol]) = v;
        }
        __syncthreads();
#pragma unroll
        for (int k = 0; k < BK; ++k) {
            float4 a4 = *reinterpret_cast<const float4*>(&As[k][ty * 4]);
            float4 b4 = *reinterpret_cast<const float4*>(&Bs[k][tx * 4]);
            float av[4] = {a4.x, a4.y, a4.z, a4.w};
            float bv[4] = {b4.x, b4.y, b4.z, b4.w};
#pragma unroll
            for (int i = 0; i < 4; ++i)
#pragma unroll
                for (int j = 0; j < 4; ++j)
                    acc[i][j] = fmaf(av[i], bv[j], acc[i][j]);
        }
        __syncthreads();
    }

    const int crow0 = bm + ty * 4;
    const int ccol0 = bn + tx * 4;
    float4 bv = make_float4(0.f, 0.f, 0.f, 0.f);
    if (EPI) bv = *reinterpret_cast<const float4*>(bias + ccol0);
#pragma unroll
    for (int i = 0; i < 4; ++i) {
        float4 v = make_float4(acc[i][0], acc[i][1], acc[i][2], acc[i][3]);
        if (EPI) {
            v.x = fmaxf(v.x + bv.x, 0.f);
            v.y = fmaxf(v.y + bv.y, 0.f);
            v.z = fmaxf(v.z + bv.z, 0.f);
            v.w = fmaxf(v.w + bv.w, 0.f);
        }
        *reinterpret_cast<float4*>(C + (size_t)(crow0 + i) * N + ccol0) = v;
    }
}

// out[i,:] = h[i,:] * disq[i]^2 + bias[:]   (also the zero-init for scatter)
__global__ __launch_bounds__(256) void self_bias_kernel(const float* __restrict__ h,
                                                        const float* __restrict__ disq,
                                                        const float* __restrict__ bias,
                                                        float* __restrict__ out, int n) {
    int t = blockIdx.x * blockDim.x + threadIdx.x;
    if (t >= n * 32) return;
    int node = t >> 5, grp = (t & 31) * 4;
    float s = disq[node];
    s = s * s;
    float4 hv = *reinterpret_cast<const float4*>(h + (size_t)node * 128 + grp);
    float4 bv = *reinterpret_cast<const float4*>(bias + grp);
    float4 o = make_float4(fmaf(hv.x, s, bv.x), fmaf(hv.y, s, bv.y),
                           fmaf(hv.z, s, bv.z), fmaf(hv.w, s, bv.w));
    *reinterpret_cast<float4*>(out + (size_t)node * 128 + grp) = o;
}

// 32 threads per edge, float4 gather + 4 scalar atomicAdds
__global__ __launch_bounds__(256) void scatter_kernel(const float* __restrict__ h,
                                                      const int* __restrict__ src,
                                                      const int* __restrict__ dst,
                                                      const float* __restrict__ disq,
                                                      float* __restrict__ out, int E) {
    int t = blockIdx.x * blockDim.x + threadIdx.x;
    if (t >= E * 32) return;
    int e = t >> 5, grp = (t & 31) * 4;
    int s = src[e], d = dst[e];
    float norm = disq[s] * disq[d];
    float4 hv = *reinterpret_cast<const float4*>(h + (size_t)s * 128 + grp);
    float* op = out + (size_t)d * 128 + grp;
    atomicAdd(op + 0, hv.x * norm);
    atomicAdd(op + 1, hv.y * norm);
    atomicAdd(op + 2, hv.z * norm);
    atomicAdd(op + 3, hv.w * norm);
}

// batch is sorted: pre-reduce runs of 8 nodes per thread, flush on boundary.
// relu applied here (pooled init = 0 handles empty graphs, matches reference).
__global__ __launch_bounds__(256) void pool_kernel(const float* __restrict__ x,
                                                   const int* __restrict__ batch,
                                                   int* __restrict__ pooled, int n) {
    int t = blockIdx.x * blockDim.x + threadIdx.x;
    int d = t & 127;
    int n0 = (t >> 7) * 8;
    if (n0 >= n) return;
    int cur = batch[n0];
    float m = fmaxf(x[(size_t)n0 * 128 + d], 0.f);
    for (int i = 1; i < 8 && (n0 + i) < n; ++i) {
        int b = batch[n0 + i];
        float v = fmaxf(x[(size_t)(n0 + i) * 128 + d], 0.f);
        if (b == cur) {
            m = fmaxf(m, v);
        } else {
            atomicMax(&pooled[cur * 128 + d], __float_as_int(m));
            cur = b;
            m = v;
        }
    }
    atomicMax(&pooled[cur * 128 + d], __float_as_int(m));
}

extern "C" void kernel_launch(void* const* d_in, const int* in_sizes, int n_in,
                              void* d_out, int out_size, void* d_ws, size_t ws_size,
                              hipStream_t stream) {
    const float* x    = (const float*)d_in[0];
    const int*   edge = (const int*)d_in[1];
    const int*   batch= (const int*)d_in[2];
    const float* gW0  = (const float*)d_in[4];
    const float* gb0  = (const float*)d_in[5];
    const float* gW1  = (const float*)d_in[6];
    const float* gb1  = (const float*)d_in[7];
    const float* gW2  = (const float*)d_in[8];
    const float* gb2  = (const float*)d_in[9];
    const float* fW0  = (const float*)d_in[10];
    const float* fb0  = (const float*)d_in[11];
    const float* fW1  = (const float*)d_in[12];
    const float* fb1  = (const float*)d_in[13];
    float* out = (float*)d_out;

    float* ws     = (float*)d_ws;
    float* h      = ws;                           // NN*128
    float* agg    = h + (size_t)NN * 128;         // NN*128
    float* disq   = agg + (size_t)NN * 128;       // NN
    float* pooled = disq + NN;                    // NG*128
    float* ffh    = pooled + (size_t)NG * 128;    // NG*256

    const int* src = edge;
    const int* dst = edge + NE;

    // degree
    fill_kernel<<<cdiv(NN, 256), 256, 0, stream>>>(disq, 1.0f, NN);
    deg_count_kernel<<<cdiv(NE, 256), 256, 0, stream>>>(dst, disq, NE);
    rsqrt_kernel<<<cdiv(NN, 256), 256, 0, stream>>>(disq, NN);

    // layer 0: x[NN,78] @ gW0 -> h; agg = h*d^-1 + b; scatter
    gemm_kernel<false, false><<<dim3(NN / 64, 2), 256, 0, stream>>>(x, gW0, nullptr, h, NN, 128, 78);
    self_bias_kernel<<<cdiv(NN * 32, 256), 256, 0, stream>>>(h, disq, gb0, agg, NN);
    scatter_kernel<<<cdiv(NE * 32, 256), 256, 0, stream>>>(h, src, dst, disq, agg, NE);

    // layer 1 (relu on load of agg)
    gemm_kernel<true, false><<<dim3(NN / 64, 2), 256, 0, stream>>>(agg, gW1, nullptr, h, NN, 128, 128);
    self_bias_kernel<<<cdiv(NN * 32, 256), 256, 0, stream>>>(h, disq, gb1, agg, NN);
    scatter_kernel<<<cdiv(NE * 32, 256), 256, 0, stream>>>(h, src, dst, disq, agg, NE);

    // layer 2
    gemm_kernel<true, false><<<dim3(NN / 64, 2), 256, 0, stream>>>(agg, gW2, nullptr, h, NN, 128, 128);
    self_bias_kernel<<<cdiv(NN * 32, 256), 256, 0, stream>>>(h, disq, gb2, agg, NN);
    scatter_kernel<<<cdiv(NE * 32, 256), 256, 0, stream>>>(h, src, dst, disq, agg, NE);

    // global max pool (relu fused)
    fill_kernel<<<cdiv(NG * 128, 256), 256, 0, stream>>>(pooled, 0.0f, NG * 128);
    pool_kernel<<<cdiv(cdiv(NN, 8) * 128, 256), 256, 0, stream>>>(agg, batch, (int*)pooled, NN);

    // FF head
    gemm_kernel<false, true><<<dim3(NG / 64, 4), 256, 0, stream>>>(pooled, fW0, fb0, ffh, NG, 256, 128);
    gemm_kernel<false, true><<<dim3(NG / 64, 2), 256, 0, stream>>>(ffh, fW1, fb1, out, NG, 128, 256);
}

// Round 2
// 1430.959 us; speedup vs baseline: 3.5656x; 3.5656x over previous
//
#include <hip/hip_runtime.h>

#define NN 400000
#define NE 800000
#define NG 16384

static inline int cdiv(int a, int b) { return (a + b - 1) / b; }

__global__ __launch_bounds__(256) void fill_kernel(float* __restrict__ p, float v, int n) {
    int i = blockIdx.x * blockDim.x + threadIdx.x;
    if (i < n) p[i] = v;
}

__global__ __launch_bounds__(256) void fill_int_kernel(int* __restrict__ p, int v, int n) {
    int i = blockIdx.x * blockDim.x + threadIdx.x;
    if (i < n) p[i] = v;
}

__global__ __launch_bounds__(256) void hist_kernel(const int* __restrict__ dst,
                                                   int* __restrict__ deg, int E) {
    int e = blockIdx.x * blockDim.x + threadIdx.x;
    if (e < E) atomicAdd(&deg[dst[e]], 1);
}

__global__ __launch_bounds__(256) void disq_kernel(const int* __restrict__ deg,
                                                   float* __restrict__ disq, int n) {
    int i = blockIdx.x * blockDim.x + threadIdx.x;
    if (i < n) disq[i] = rsqrtf(1.0f + (float)deg[i]);
}

// ---- 3-pass exclusive scan over int array (block = 256 thr x 8 elems = 2048) ----
#define SCAN_TPB 256
#define SCAN_EPT 8
#define SCAN_BE (SCAN_TPB * SCAN_EPT)

__global__ __launch_bounds__(SCAN_TPB) void scan_a_kernel(const int* __restrict__ in,
                                                          int* __restrict__ out,
                                                          int* __restrict__ partials, int n) {
    __shared__ int sums[SCAN_TPB];
    const int tid = threadIdx.x;
    int base = blockIdx.x * SCAN_BE + tid * SCAN_EPT;
    int v[SCAN_EPT];
    int s = 0;
#pragma unroll
    for (int i = 0; i < SCAN_EPT; ++i) {
        int idx = base + i;
        int x = (idx < n) ? in[idx] : 0;
        v[i] = s;  // exclusive within thread
        s += x;
    }
    sums[tid] = s;
    __syncthreads();
    for (int off = 1; off < SCAN_TPB; off <<= 1) {
        int t = (tid >= off) ? sums[tid - off] : 0;
        __syncthreads();
        sums[tid] += t;
        __syncthreads();
    }
    int toff = (tid == 0) ? 0 : sums[tid - 1];
#pragma unroll
    for (int i = 0; i < SCAN_EPT; ++i) {
        int idx = base + i;
        if (idx < n) out[idx] = toff + v[i];
    }
    if (tid == SCAN_TPB - 1) partials[blockIdx.x] = sums[SCAN_TPB - 1];
}

__global__ void scan_b_kernel(int* __restrict__ partials, int nb) {
    if (blockIdx.x == 0 && threadIdx.x == 0) {
        int s = 0;
        for (int i = 0; i < nb; ++i) { int x = partials[i]; partials[i] = s; s += x; }
    }
}

__global__ __launch_bounds__(256) void scan_c_kernel(int* __restrict__ out,
                                                     const int* __restrict__ partials, int n) {
    int idx = blockIdx.x * blockDim.x + threadIdx.x;
    if (idx < n) out[idx] += partials[idx / SCAN_BE];
}

// ---- CSR fill: place each edge into its dst row ----
__global__ __launch_bounds__(256) void csr_fill_kernel(const int* __restrict__ src,
                                                       const int* __restrict__ dst,
                                                       const int* __restrict__ rowptr,
                                                       int* __restrict__ cnt,
                                                       const float* __restrict__ disq,
                                                       int* __restrict__ csr_src,
                                                       float* __restrict__ csr_norm, int E) {
    int e = blockIdx.x * blockDim.x + threadIdx.x;
    if (e >= E) return;
    int d = dst[e], s = src[e];
    int pos = rowptr[d] + atomicAdd(&cnt[d], 1);
    csr_src[pos] = s;
    csr_norm[pos] = disq[s] * disq[d];
}

// ---- CSR gather aggregation: out[d] = h[d]*disq[d]^2 + b + sum_in h[s]*norm ----
// 32 lanes per node, one float4 per lane. Single write per row, no atomics.
__global__ __launch_bounds__(256) void gather_kernel(const float* __restrict__ h,
                                                     const int* __restrict__ rowptr,
                                                     const int* __restrict__ deg,
                                                     const int* __restrict__ csr_src,
                                                     const float* __restrict__ csr_norm,
                                                     const float* __restrict__ disq,
                                                     const float* __restrict__ bias,
                                                     float* __restrict__ out, int n) {
    int t = blockIdx.x * blockDim.x + threadIdx.x;
    if (t >= n * 32) return;
    int node = t >> 5, q = (t & 31) * 4;
    float si = disq[node];
    float s2 = si * si;
    float4 bv = *reinterpret_cast<const float4*>(bias + q);
    float4 hv = *reinterpret_cast<const float4*>(h + (size_t)node * 128 + q);
    float4 acc = make_float4(fmaf(hv.x, s2, bv.x), fmaf(hv.y, s2, bv.y),
                             fmaf(hv.z, s2, bv.z), fmaf(hv.w, s2, bv.w));
    int beg = rowptr[node];
    int end = beg + deg[node];
    for (int j = beg; j < end; ++j) {
        int sidx = csr_src[j];
        float nrm = csr_norm[j];
        float4 v = *reinterpret_cast<const float4*>(h + (size_t)sidx * 128 + q);
        acc.x = fmaf(v.x, nrm, acc.x);
        acc.y = fmaf(v.y, nrm, acc.y);
        acc.z = fmaf(v.z, nrm, acc.z);
        acc.w = fmaf(v.w, nrm, acc.w);
    }
    *reinterpret_cast<float4*>(out + (size_t)node * 128 + q) = acc;
}

// C[M,N] = act(A)[M,K] @ B[K,N]  (+bias, relu if EPI)
template <bool RELU_A, bool EPI>
__global__ __launch_bounds__(256) void gemm_kernel(const float* __restrict__ A,
                                                   const float* __restrict__ B,
                                                   const float* __restrict__ bias,
                                                   float* __restrict__ C,
                                                   int M, int N, int K) {
    const int BM = 64, BN = 64, BK = 16;
    __shared__ float As[BK][BM + 4];
    __shared__ float Bs[BK][BN + 4];

    const int tid = threadIdx.x;
    const int bm = blockIdx.x * BM;
    const int bn = blockIdx.y * BN;
    const int tx = tid & 15;
    const int ty = tid >> 4;

    const int arow = tid >> 2;
    const int acol = (tid & 3) * 4;
    const int brow = tid >> 4;
    const int bcol = (tid & 15) * 4;

    float acc[4][4] = {};

    for (int k0 = 0; k0 < K; k0 += BK) {
        {
            const float* ap = A + (size_t)(bm + arow) * K;
#pragma unroll
            for (int j = 0; j < 4; ++j) {
                int kk = k0 + acol + j;
                float v = (kk < K) ? ap[kk] : 0.0f;
                if (RELU_A) v = fmaxf(v, 0.0f);
                As[acol + j][arow] = v;
            }
        }
        {
            int kk = k0 + brow;
            float4 v = make_float4(0.f, 0.f, 0.f, 0.f);
            if (kk < K) v = *reinterpret_cast<const float4*>(B + (size_t)kk * N + bn + bcol);
            *reinterpret_cast<float4*>(&Bs[brow][bcol]) = v;
        }
        __syncthreads();
#pragma unroll
        for (int k = 0; k < BK; ++k) {
            float4 a4 = *reinterpret_cast<const float4*>(&As[k][ty * 4]);
            float4 b4 = *reinterpret_cast<const float4*>(&Bs[k][tx * 4]);
            float av[4] = {a4.x, a4.y, a4.z, a4.w};
            float bv[4] = {b4.x, b4.y, b4.z, b4.w};
#pragma unroll
            for (int i = 0; i < 4; ++i)
#pragma unroll
                for (int j = 0; j < 4; ++j)
                    acc[i][j] = fmaf(av[i], bv[j], acc[i][j]);
        }
        __syncthreads();
    }

    const int crow0 = bm + ty * 4;
    const int ccol0 = bn + tx * 4;
    float4 bv = make_float4(0.f, 0.f, 0.f, 0.f);
    if (EPI) bv = *reinterpret_cast<const float4*>(bias + ccol0);
#pragma unroll
    for (int i = 0; i < 4; ++i) {
        float4 v = make_float4(acc[i][0], acc[i][1], acc[i][2], acc[i][3]);
        if (EPI) {
            v.x = fmaxf(v.x + bv.x, 0.f);
            v.y = fmaxf(v.y + bv.y, 0.f);
            v.z = fmaxf(v.z + bv.z, 0.f);
            v.w = fmaxf(v.w + bv.w, 0.f);
        }
        *reinterpret_cast<float4*>(C + (size_t)(crow0 + i) * N + ccol0) = v;
    }
}

// batch is sorted: pre-reduce runs of 8 nodes, flush on boundary. relu fused.
__global__ __launch_bounds__(256) void pool_kernel(const float* __restrict__ x,
                                                   const int* __restrict__ batch,
                                                   int* __restrict__ pooled, int n) {
    int t = blockIdx.x * blockDim.x + threadIdx.x;
    int d = t & 127;
    int n0 = (t >> 7) * 8;
    if (n0 >= n) return;
    int cur = batch[n0];
    float m = fmaxf(x[(size_t)n0 * 128 + d], 0.f);
    for (int i = 1; i < 8 && (n0 + i) < n; ++i) {
        int b = batch[n0 + i];
        float v = fmaxf(x[(size_t)(n0 + i) * 128 + d], 0.f);
        if (b == cur) {
            m = fmaxf(m, v);
        } else {
            atomicMax(&pooled[cur * 128 + d], __float_as_int(m));
            cur = b;
            m = v;
        }
    }
    atomicMax(&pooled[cur * 128 + d], __float_as_int(m));
}

extern "C" void kernel_launch(void* const* d_in, const int* in_sizes, int n_in,
                              void* d_out, int out_size, void* d_ws, size_t ws_size,
                              hipStream_t stream) {
    const float* x    = (const float*)d_in[0];
    const int*   edge = (const int*)d_in[1];
    const int*   batch= (const int*)d_in[2];
    const float* gW0  = (const float*)d_in[4];
    const float* gb0  = (const float*)d_in[5];
    const float* gW1  = (const float*)d_in[6];
    const float* gb1  = (const float*)d_in[7];
    const float* gW2  = (const float*)d_in[8];
    const float* gb2  = (const float*)d_in[9];
    const float* fW0  = (const float*)d_in[10];
    const float* fb0  = (const float*)d_in[11];
    const float* fW1  = (const float*)d_in[12];
    const float* fb1  = (const float*)d_in[13];
    float* out = (float*)d_out;

    float* ws     = (float*)d_ws;
    float* h      = ws;                           // NN*128
    float* agg    = h + (size_t)NN * 128;         // NN*128
    float* disq   = agg + (size_t)NN * 128;       // NN
    float* pooled = disq + NN;                    // NG*128
    float* ffh    = pooled + (size_t)NG * 128;    // NG*256

    // CSR scratch aliases regions with disjoint lifetimes:
    //  - cnt aliases pooled (pooled written only after last gather)
    //  - deg/rowptr/csr_* alias ffh (ffh written only in FF head)
    int*   cnt      = (int*)pooled;               // NN
    int*   deg      = (int*)ffh;                  // NN
    int*   rowptr   = deg + NN;                   // NN
    int*   csr_src  = rowptr + NN;                // NE
    float* csr_norm = (float*)(csr_src + NE);     // NE
    int*   partials = (int*)(csr_norm + NE);      // ~200

    const int* src = edge;
    const int* dst = edge + NE;

    // ---- degree + disq + CSR build ----
    fill_int_kernel<<<cdiv(NN, 256), 256, 0, stream>>>(deg, 0, NN);
    fill_int_kernel<<<cdiv(NN, 256), 256, 0, stream>>>(cnt, 0, NN);
    hist_kernel<<<cdiv(NE, 256), 256, 0, stream>>>(dst, deg, NE);
    disq_kernel<<<cdiv(NN, 256), 256, 0, stream>>>(deg, disq, NN);
    int nsb = cdiv(NN, SCAN_BE);
    scan_a_kernel<<<nsb, SCAN_TPB, 0, stream>>>(deg, rowptr, partials, NN);
    scan_b_kernel<<<1, 64, 0, stream>>>(partials, nsb);
    scan_c_kernel<<<cdiv(NN, 256), 256, 0, stream>>>(rowptr, partials, NN);
    csr_fill_kernel<<<cdiv(NE, 256), 256, 0, stream>>>(src, dst, rowptr, cnt, disq,
                                                       csr_src, csr_norm, NE);

    // ---- layer 0 ----
    gemm_kernel<false, false><<<dim3(NN / 64, 2), 256, 0, stream>>>(x, gW0, nullptr, h, NN, 128, 78);
    gather_kernel<<<cdiv(NN * 32, 256), 256, 0, stream>>>(h, rowptr, deg, csr_src, csr_norm,
                                                          disq, gb0, agg, NN);
    // ---- layer 1 ----
    gemm_kernel<true, false><<<dim3(NN / 64, 2), 256, 0, stream>>>(agg, gW1, nullptr, h, NN, 128, 128);
    gather_kernel<<<cdiv(NN * 32, 256), 256, 0, stream>>>(h, rowptr, deg, csr_src, csr_norm,
                                                          disq, gb1, agg, NN);
    // ---- layer 2 ----
    gemm_kernel<true, false><<<dim3(NN / 64, 2), 256, 0, stream>>>(agg, gW2, nullptr, h, NN, 128, 128);
    gather_kernel<<<cdiv(NN * 32, 256), 256, 0, stream>>>(h, rowptr, deg, csr_src, csr_norm,
                                                          disq, gb2, agg, NN);

    // ---- global max pool (relu fused) ----
    fill_kernel<<<cdiv(NG * 128, 256), 256, 0, stream>>>(pooled, 0.0f, NG * 128);
    pool_kernel<<<cdiv(cdiv(NN, 8) * 128, 256), 256, 0, stream>>>(agg, batch, (int*)pooled, NN);

    // ---- FF head ----
    gemm_kernel<false, true><<<dim3(NG / 64, 4), 256, 0, stream>>>(pooled, fW0, fb0, ffh, NG, 256, 128);
    gemm_kernel<false, true><<<dim3(NG / 64, 2), 256, 0, stream>>>(ffh, fW1, fb1, out, NG, 128, 256);
}

// Round 3
// 1118.149 us; speedup vs baseline: 4.5631x; 1.2798x over previous
//
#include <hip/hip_runtime.h>

#define NN 400000
#define NE 800000
#define NG 16384

typedef short bf16x8 __attribute__((ext_vector_type(8)));
typedef float f32x4 __attribute__((ext_vector_type(4)));

static inline int cdiv(int a, int b) { return (a + b - 1) / b; }

__device__ inline unsigned short bf16_rne(float v) {
    unsigned u = __float_as_uint(v);
    unsigned r = u + 0x7FFFu + ((u >> 16) & 1u);
    return (unsigned short)(r >> 16);
}
__device__ inline float bf16_to_f(unsigned short h) {
    return __uint_as_float(((unsigned)h) << 16);
}
__device__ inline void split2(float v, unsigned short& hi, unsigned short& lo) {
    hi = bf16_rne(v);
    lo = bf16_rne(v - bf16_to_f(hi));
}

__global__ __launch_bounds__(256) void fill_kernel(float* __restrict__ p, float v, int n) {
    int i = blockIdx.x * blockDim.x + threadIdx.x;
    if (i < n) p[i] = v;
}

__global__ __launch_bounds__(256) void fill_int_kernel(int* __restrict__ p, int v, int n) {
    int i = blockIdx.x * blockDim.x + threadIdx.x;
    if (i < n) p[i] = v;
}

__global__ __launch_bounds__(256) void hist_kernel(const int* __restrict__ dst,
                                                   int* __restrict__ deg, int E) {
    int e = blockIdx.x * blockDim.x + threadIdx.x;
    if (e < E) atomicAdd(&deg[dst[e]], 1);
}

__global__ __launch_bounds__(256) void disq_kernel(const int* __restrict__ deg,
                                                   float* __restrict__ disq, int n) {
    int i = blockIdx.x * blockDim.x + threadIdx.x;
    if (i < n) disq[i] = rsqrtf(1.0f + (float)deg[i]);
}

// ---- 3-pass exclusive scan ----
#define SCAN_TPB 256
#define SCAN_EPT 8
#define SCAN_BE (SCAN_TPB * SCAN_EPT)

__global__ __launch_bounds__(SCAN_TPB) void scan_a_kernel(const int* __restrict__ in,
                                                          int* __restrict__ out,
                                                          int* __restrict__ partials, int n) {
    __shared__ int sums[SCAN_TPB];
    const int tid = threadIdx.x;
    int base = blockIdx.x * SCAN_BE + tid * SCAN_EPT;
    int v[SCAN_EPT];
    int s = 0;
#pragma unroll
    for (int i = 0; i < SCAN_EPT; ++i) {
        int idx = base + i;
        int x = (idx < n) ? in[idx] : 0;
        v[i] = s;
        s += x;
    }
    sums[tid] = s;
    __syncthreads();
    for (int off = 1; off < SCAN_TPB; off <<= 1) {
        int t = (tid >= off) ? sums[tid - off] : 0;
        __syncthreads();
        sums[tid] += t;
        __syncthreads();
    }
    int toff = (tid == 0) ? 0 : sums[tid - 1];
#pragma unroll
    for (int i = 0; i < SCAN_EPT; ++i) {
        int idx = base + i;
        if (idx < n) out[idx] = toff + v[i];
    }
    if (tid == SCAN_TPB - 1) partials[blockIdx.x] = sums[SCAN_TPB - 1];
}

__global__ void scan_b_kernel(int* __restrict__ partials, int nb) {
    if (blockIdx.x == 0 && threadIdx.x == 0) {
        int s = 0;
        for (int i = 0; i < nb; ++i) { int x = partials[i]; partials[i] = s; s += x; }
    }
}

__global__ __launch_bounds__(256) void scan_c_kernel(int* __restrict__ out,
                                                     const int* __restrict__ partials, int n) {
    int idx = blockIdx.x * blockDim.x + threadIdx.x;
    if (idx < n) out[idx] += partials[idx / SCAN_BE];
}

__global__ __launch_bounds__(256) void csr_fill_kernel(const int* __restrict__ src,
                                                       const int* __restrict__ dst,
                                                       const int* __restrict__ rowptr,
                                                       int* __restrict__ cnt,
                                                       const float* __restrict__ disq,
                                                       int* __restrict__ csr_src,
                                                       float* __restrict__ csr_norm, int E) {
    int e = blockIdx.x * blockDim.x + threadIdx.x;
    if (e >= E) return;
    int d = dst[e], s = src[e];
    int pos = rowptr[d] + atomicAdd(&cnt[d], 1);
    csr_src[pos] = s;
    csr_norm[pos] = disq[s] * disq[d];
}

// ---- weight prep: W[K][128] fp32 -> transposed, split, XOR-swizzled planes ----
// plane layout: n in 0..127 rows of 128 bf16 (256B); 16B granule index ^= (n&7)
__global__ __launch_bounds__(256) void prep_w_kernel(const float* __restrict__ W, int K,
                                                     unsigned short* __restrict__ planeHi,
                                                     unsigned short* __restrict__ planeLo) {
    int i = blockIdx.x * blockDim.x + threadIdx.x;
    if (i >= 128 * 128) return;
    int n = i >> 7, k = i & 127;
    float v = (k < K) ? W[k * 128 + n] : 0.0f;
    unsigned short hi, lo;
    split2(v, hi, lo);
    int elem = (n * 256 + ((2 * k) ^ ((n & 7) << 4))) >> 1;
    planeHi[elem] = hi;
    planeLo[elem] = lo;
}

// ---- x convert: [NN][78] fp32 -> hi/lo bf16 [NN][96] (zero pad) ----
__global__ __launch_bounds__(256) void xconv_kernel(const float* __restrict__ x,
                                                    unsigned short* __restrict__ xHi,
                                                    unsigned short* __restrict__ xLo) {
    long long t = (long long)blockIdx.x * blockDim.x + threadIdx.x;
    if (t >= (long long)NN * 96) return;
    int node = (int)(t / 96), k = (int)(t - (long long)node * 96);
    float v = (k < 78) ? x[(size_t)node * 78 + k] : 0.0f;
    unsigned short hi, lo;
    split2(v, hi, lo);
    size_t o = (size_t)node * 96 + k;
    xHi[o] = hi;
    xLo[o] = lo;
}

// ---- split-bf16 MFMA GEMM: C[M,128] = (Ahi+Alo)[M,K] @ (Whi+Wlo)[K,128] ----
// A planes row-major stride AS; WT planes: swizzled [128][128] (see prep_w).
// Block: 256 thr = 4 waves; each block does RT row-tiles of 64 rows;
// wave w owns 16 rows, all 128 cols (8 col-tiles of 16).
template <int NKC, int AS>
__global__ __launch_bounds__(256) void gemm_mfma_kernel(const unsigned short* __restrict__ Ahi,
                                                        const unsigned short* __restrict__ Alo,
                                                        const unsigned short* __restrict__ WT,
                                                        float* __restrict__ C, int M) {
    __shared__ unsigned short lds[2 * 128 * 128];  // hi plane, lo plane (64 KiB)
    const int tid = threadIdx.x;
    {
        const unsigned* s = reinterpret_cast<const unsigned*>(WT);
        unsigned* d = reinterpret_cast<unsigned*>(lds);
#pragma unroll
        for (int i = 0; i < 64; ++i) d[tid + 256 * i] = s[tid + 256 * i];
    }
    __syncthreads();

    const int w = tid >> 6, lane = tid & 63;
    const int m = lane & 15, kb = lane >> 4;
    const char* ldsHiB = reinterpret_cast<const char*>(lds);
    const char* ldsLoB = ldsHiB + 128 * 256;

    const int RT = 4;
    for (int rt = 0; rt < RT; ++rt) {
        int row0 = (blockIdx.x * RT + rt) * 64;
        if (row0 >= M) return;
        int arow = row0 + w * 16 + m;

        bf16x8 ah[NKC], al[NKC];
#pragma unroll
        for (int kc = 0; kc < NKC; ++kc) {
            size_t off = (size_t)arow * AS + kc * 32 + kb * 8;
            ah[kc] = *reinterpret_cast<const bf16x8*>(Ahi + off);
            al[kc] = *reinterpret_cast<const bf16x8*>(Alo + off);
        }

        f32x4 acc[8];
#pragma unroll
        for (int ct = 0; ct < 8; ++ct)
#pragma unroll
            for (int r = 0; r < 4; ++r) acc[ct][r] = 0.0f;

#pragma unroll
        for (int ct = 0; ct < 8; ++ct) {
            int n = ct * 16 + m;
            int swz = (n & 7) << 4;
            int rowb = n * 256;
#pragma unroll
            for (int kc = 0; kc < NKC; ++kc) {
                int bb = rowb + ((kc * 64 + kb * 16) ^ swz);
                bf16x8 bh = *reinterpret_cast<const bf16x8*>(ldsHiB + bb);
                bf16x8 bl = *reinterpret_cast<const bf16x8*>(ldsLoB + bb);
                acc[ct] = __builtin_amdgcn_mfma_f32_16x16x32_bf16(ah[kc], bh, acc[ct], 0, 0, 0);
                acc[ct] = __builtin_amdgcn_mfma_f32_16x16x32_bf16(ah[kc], bl, acc[ct], 0, 0, 0);
                acc[ct] = __builtin_amdgcn_mfma_f32_16x16x32_bf16(al[kc], bh, acc[ct], 0, 0, 0);
            }
        }

        // C/D layout: col = lane&15, row = (lane>>4)*4 + r   [m89]
        float* cp = C + (size_t)(row0 + w * 16) * 128;
#pragma unroll
        for (int ct = 0; ct < 8; ++ct)
#pragma unroll
            for (int r = 0; r < 4; ++r)
                cp[(size_t)(kb * 4 + r) * 128 + ct * 16 + m] = acc[ct][r];
    }
}

// ---- CSR gather: out = relu(h*disq^2 + b + sum h[src]*norm), split to planes ----
__global__ __launch_bounds__(256) void gather_kernel(const float* __restrict__ h,
                                                     const int* __restrict__ rowptr,
                                                     const int* __restrict__ deg,
                                                     const int* __restrict__ csr_src,
                                                     const float* __restrict__ csr_norm,
                                                     const float* __restrict__ disq,
                                                     const float* __restrict__ bias,
                                                     unsigned short* __restrict__ outHi,
                                                     unsigned short* __restrict__ outLo, int n) {
    int t = blockIdx.x * blockDim.x + threadIdx.x;
    if (t >= n * 32) return;
    int node = t >> 5, q = (t & 31) * 4;
    float si = disq[node];
    float s2 = si * si;
    float4 bv = *reinterpret_cast<const float4*>(bias + q);
    float4 hv = *reinterpret_cast<const float4*>(h + (size_t)node * 128 + q);
    float4 acc = make_float4(fmaf(hv.x, s2, bv.x), fmaf(hv.y, s2, bv.y),
                             fmaf(hv.z, s2, bv.z), fmaf(hv.w, s2, bv.w));
    int beg = rowptr[node];
    int end = beg + deg[node];
    for (int j = beg; j < end; ++j) {
        int sidx = csr_src[j];
        float nrm = csr_norm[j];
        float4 v = *reinterpret_cast<const float4*>(h + (size_t)sidx * 128 + q);
        acc.x = fmaf(v.x, nrm, acc.x);
        acc.y = fmaf(v.y, nrm, acc.y);
        acc.z = fmaf(v.z, nrm, acc.z);
        acc.w = fmaf(v.w, nrm, acc.w);
    }
    float av[4] = {fmaxf(acc.x, 0.f), fmaxf(acc.y, 0.f), fmaxf(acc.z, 0.f), fmaxf(acc.w, 0.f)};
    ushort4 h4, l4;
    split2(av[0], h4.x, l4.x);
    split2(av[1], h4.y, l4.y);
    split2(av[2], h4.z, l4.z);
    split2(av[3], h4.w, l4.w);
    size_t o = (size_t)node * 128 + q;
    *reinterpret_cast<ushort4*>(outHi + o) = h4;
    *reinterpret_cast<ushort4*>(outLo + o) = l4;
}

// fp32 VALU GEMM for the small FF head
template <bool RELU_A, bool EPI>
__global__ __launch_bounds__(256) void gemm_kernel(const float* __restrict__ A,
                                                   const float* __restrict__ B,
                                                   const float* __restrict__ bias,
                                                   float* __restrict__ C,
                                                   int M, int N, int K) {
    const int BM = 64, BN = 64, BK = 16;
    __shared__ float As[BK][BM + 4];
    __shared__ float Bs[BK][BN + 4];

    const int tid = threadIdx.x;
    const int bm = blockIdx.x * BM;
    const int bn = blockIdx.y * BN;
    const int tx = tid & 15;
    const int ty = tid >> 4;

    const int arow = tid >> 2;
    const int acol = (tid & 3) * 4;
    const int brow = tid >> 4;
    const int bcol = (tid & 15) * 4;

    float acc[4][4] = {};

    for (int k0 = 0; k0 < K; k0 += BK) {
        {
            const float* ap = A + (size_t)(bm + arow) * K;
#pragma unroll
            for (int j = 0; j < 4; ++j) {
                int kk = k0 + acol + j;
                float v = (kk < K) ? ap[kk] : 0.0f;
                if (RELU_A) v = fmaxf(v, 0.0f);
                As[acol + j][arow] = v;
            }
        }
        {
            int kk = k0 + brow;
            float4 v = make_float4(0.f, 0.f, 0.f, 0.f);
            if (kk < K) v = *reinterpret_cast<const float4*>(B + (size_t)kk * N + bn + bcol);
            *reinterpret_cast<float4*>(&Bs[brow][bcol]) = v;
        }
        __syncthreads();
#pragma unroll
        for (int k = 0; k < BK; ++k) {
            float4 a4 = *reinterpret_cast<const float4*>(&As[k][ty * 4]);
            float4 b4 = *reinterpret_cast<const float4*>(&Bs[k][tx * 4]);
            float av[4] = {a4.x, a4.y, a4.z, a4.w};
            float bv[4] = {b4.x, b4.y, b4.z, b4.w};
#pragma unroll
            for (int i = 0; i < 4; ++i)
#pragma unroll
                for (int j = 0; j < 4; ++j)
                    acc[i][j] = fmaf(av[i], bv[j], acc[i][j]);
        }
        __syncthreads();
    }

    const int crow0 = bm + ty * 4;
    const int ccol0 = bn + tx * 4;
    float4 bv = make_float4(0.f, 0.f, 0.f, 0.f);
    if (EPI) bv = *reinterpret_cast<const float4*>(bias + ccol0);
#pragma unroll
    for (int i = 0; i < 4; ++i) {
        float4 v = make_float4(acc[i][0], acc[i][1], acc[i][2], acc[i][3]);
        if (EPI) {
            v.x = fmaxf(v.x + bv.x, 0.f);
            v.y = fmaxf(v.y + bv.y, 0.f);
            v.z = fmaxf(v.z + bv.z, 0.f);
            v.w = fmaxf(v.w + bv.w, 0.f);
        }
        *reinterpret_cast<float4*>(C + (size_t)(crow0 + i) * N + ccol0) = v;
    }
}

// batch sorted: pre-reduce runs of 8 nodes, flush on boundary. reads hi/lo planes.
__global__ __launch_bounds__(256) void pool_kernel(const unsigned short* __restrict__ xHi,
                                                   const unsigned short* __restrict__ xLo,
                                                   const int* __restrict__ batch,
                                                   int* __restrict__ pooled, int n) {
    int t = blockIdx.x * blockDim.x + threadIdx.x;
    int d = t & 127;
    int n0 = (t >> 7) * 8;
    if (n0 >= n) return;
    int cur = batch[n0];
    size_t o = (size_t)n0 * 128 + d;
    float m = fmaxf(bf16_to_f(xHi[o]) + bf16_to_f(xLo[o]), 0.f);
    for (int i = 1; i < 8 && (n0 + i) < n; ++i) {
        int b = batch[n0 + i];
        size_t oi = (size_t)(n0 + i) * 128 + d;
        float v = fmaxf(bf16_to_f(xHi[oi]) + bf16_to_f(xLo[oi]), 0.f);
        if (b == cur) {
            m = fmaxf(m, v);
        } else {
            atomicMax(&pooled[cur * 128 + d], __float_as_int(m));
            cur = b;
            m = v;
        }
    }
    atomicMax(&pooled[cur * 128 + d], __float_as_int(m));
}

extern "C" void kernel_launch(void* const* d_in, const int* in_sizes, int n_in,
                              void* d_out, int out_size, void* d_ws, size_t ws_size,
                              hipStream_t stream) {
    const float* x    = (const float*)d_in[0];
    const int*   edge = (const int*)d_in[1];
    const int*   batch= (const int*)d_in[2];
    const float* gW0  = (const float*)d_in[4];
    const float* gb0  = (const float*)d_in[5];
    const float* gW1  = (const float*)d_in[6];
    const float* gb1  = (const float*)d_in[7];
    const float* gW2  = (const float*)d_in[8];
    const float* gb2  = (const float*)d_in[9];
    const float* fW0  = (const float*)d_in[10];
    const float* fb0  = (const float*)d_in[11];
    const float* fW1  = (const float*)d_in[12];
    const float* fb1  = (const float*)d_in[13];
    float* out = (float*)d_out;

    float* ws = (float*)d_ws;
    float* h = ws;                                            // NN*128 f32
    unsigned short* aggHi = (unsigned short*)(h + (size_t)NN * 128);  // NN*128 bf16
    unsigned short* aggLo = aggHi + (size_t)NN * 128;                 // NN*128 bf16
    float* disq   = (float*)(aggLo + (size_t)NN * 128);       // NN
    float* pooled = disq + NN;                                // NG*128
    float* ffh    = pooled + (size_t)NG * 128;                // NG*256

    // aliases (disjoint lifetimes):
    int*   cnt      = (int*)pooled;              // dead before pool init
    int*   deg      = (int*)ffh;                 // ffh written only by FF head (last)
    int*   rowptr   = deg + NN;
    int*   csr_src  = rowptr + NN;
    float* csr_norm = (float*)(csr_src + NE);
    unsigned short* wt0 = (unsigned short*)(csr_norm + NE);   // 2*128*128 each
    unsigned short* wt1 = wt0 + 2 * 128 * 128;
    unsigned short* wt2 = wt1 + 2 * 128 * 128;
    int* partials = (int*)(wt2 + 2 * 128 * 128);              // ~200 ints
    unsigned short* xHi = aggHi;                 // x planes dead once h0 computed
    unsigned short* xLo = aggLo;

    const int* src = edge;
    const int* dst = edge + NE;

    // ---- degree + disq + CSR build + weight prep + x convert ----
    fill_int_kernel<<<cdiv(NN, 256), 256, 0, stream>>>(deg, 0, NN);
    fill_int_kernel<<<cdiv(NN, 256), 256, 0, stream>>>(cnt, 0, NN);
    hist_kernel<<<cdiv(NE, 256), 256, 0, stream>>>(dst, deg, NE);
    disq_kernel<<<cdiv(NN, 256), 256, 0, stream>>>(deg, disq, NN);
    int nsb = cdiv(NN, SCAN_BE);
    scan_a_kernel<<<nsb, SCAN_TPB, 0, stream>>>(deg, rowptr, partials, NN);
    scan_b_kernel<<<1, 64, 0, stream>>>(partials, nsb);
    scan_c_kernel<<<cdiv(NN, 256), 256, 0, stream>>>(rowptr, partials, NN);
    csr_fill_kernel<<<cdiv(NE, 256), 256, 0, stream>>>(src, dst, rowptr, cnt, disq,
                                                       csr_src, csr_norm, NE);
    prep_w_kernel<<<64, 256, 0, stream>>>(gW0, 78, wt0, wt0 + 128 * 128);
    prep_w_kernel<<<64, 256, 0, stream>>>(gW1, 128, wt1, wt1 + 128 * 128);
    prep_w_kernel<<<64, 256, 0, stream>>>(gW2, 128, wt2, wt2 + 128 * 128);
    xconv_kernel<<<cdiv(NN * 96, 256), 256, 0, stream>>>(x, xHi, xLo);

    const int gemm_blocks = cdiv(NN / 64, 4);

    // ---- layer 0 ----
    gemm_mfma_kernel<3, 96><<<gemm_blocks, 256, 0, stream>>>(xHi, xLo, wt0, h, NN);
    gather_kernel<<<cdiv(NN * 32, 256), 256, 0, stream>>>(h, rowptr, deg, csr_src, csr_norm,
                                                          disq, gb0, aggHi, aggLo, NN);
    // ---- layer 1 ----
    gemm_mfma_kernel<4, 128><<<gemm_blocks, 256, 0, stream>>>(aggHi, aggLo, wt1, h, NN);
    gather_kernel<<<cdiv(NN * 32, 256), 256, 0, stream>>>(h, rowptr, deg, csr_src, csr_norm,
                                                          disq, gb1, aggHi, aggLo, NN);
    // ---- layer 2 ----
    gemm_mfma_kernel<4, 128><<<gemm_blocks, 256, 0, stream>>>(aggHi, aggLo, wt2, h, NN);
    gather_kernel<<<cdiv(NN * 32, 256), 256, 0, stream>>>(h, rowptr, deg, csr_src, csr_norm,
                                                          disq, gb2, aggHi, aggLo, NN);

    // ---- global max pool (relu'd planes) ----
    fill_kernel<<<cdiv(NG * 128, 256), 256, 0, stream>>>(pooled, 0.0f, NG * 128);
    pool_kernel<<<cdiv(cdiv(NN, 8) * 128, 256), 256, 0, stream>>>(aggHi, aggLo, batch,
                                                                  (int*)pooled, NN);

    // ---- FF head (small, fp32 VALU) ----
    gemm_kernel<false, true><<<dim3(NG / 64, 4), 256, 0, stream>>>(pooled, fW0, fb0, ffh, NG, 256, 128);
    gemm_kernel<false, true><<<dim3(NG / 64, 2), 256, 0, stream>>>(ffh, fW1, fb1, out, NG, 128, 256);
}

// Round 4
// 1046.369 us; speedup vs baseline: 4.8762x; 1.0686x over previous
//
#include <hip/hip_runtime.h>

#define NN 400000
#define NE 800000
#define NG 16384

typedef short bf16x8 __attribute__((ext_vector_type(8)));
typedef float f32x4 __attribute__((ext_vector_type(4)));

static inline int cdiv(int a, int b) { return (a + b - 1) / b; }

__device__ inline unsigned short bf16_rne(float v) {
    unsigned u = __float_as_uint(v);
    unsigned r = u + 0x7FFFu + ((u >> 16) & 1u);
    return (unsigned short)(r >> 16);
}
__device__ inline float bf16_to_f(unsigned short h) {
    return __uint_as_float(((unsigned)h) << 16);
}
__device__ inline void split2(float v, unsigned short& hi, unsigned short& lo) {
    hi = bf16_rne(v);
    lo = bf16_rne(v - bf16_to_f(hi));
}

__global__ __launch_bounds__(256) void fill_kernel(float* __restrict__ p, float v, int n) {
    int i = blockIdx.x * blockDim.x + threadIdx.x;
    if (i < n) p[i] = v;
}

__global__ __launch_bounds__(256) void fill_int_kernel(int* __restrict__ p, int v, int n) {
    int i = blockIdx.x * blockDim.x + threadIdx.x;
    if (i < n) p[i] = v;
}

__global__ __launch_bounds__(256) void hist_kernel(const int* __restrict__ dst,
                                                   int* __restrict__ deg, int E) {
    int e = blockIdx.x * blockDim.x + threadIdx.x;
    if (e < E) atomicAdd(&deg[dst[e]], 1);
}

__global__ __launch_bounds__(256) void disq_kernel(const int* __restrict__ deg,
                                                   float* __restrict__ disq, int n) {
    int i = blockIdx.x * blockDim.x + threadIdx.x;
    if (i < n) disq[i] = rsqrtf(1.0f + (float)deg[i]);
}

// ---- 3-pass exclusive scan ----
#define SCAN_TPB 256
#define SCAN_EPT 8
#define SCAN_BE (SCAN_TPB * SCAN_EPT)

__global__ __launch_bounds__(SCAN_TPB) void scan_a_kernel(const int* __restrict__ in,
                                                          int* __restrict__ out,
                                                          int* __restrict__ partials, int n) {
    __shared__ int sums[SCAN_TPB];
    const int tid = threadIdx.x;
    int base = blockIdx.x * SCAN_BE + tid * SCAN_EPT;
    int v[SCAN_EPT];
    int s = 0;
#pragma unroll
    for (int i = 0; i < SCAN_EPT; ++i) {
        int idx = base + i;
        int x = (idx < n) ? in[idx] : 0;
        v[i] = s;
        s += x;
    }
    sums[tid] = s;
    __syncthreads();
    for (int off = 1; off < SCAN_TPB; off <<= 1) {
        int t = (tid >= off) ? sums[tid - off] : 0;
        __syncthreads();
        sums[tid] += t;
        __syncthreads();
    }
    int toff = (tid == 0) ? 0 : sums[tid - 1];
#pragma unroll
    for (int i = 0; i < SCAN_EPT; ++i) {
        int idx = base + i;
        if (idx < n) out[idx] = toff + v[i];
    }
    if (tid == SCAN_TPB - 1) partials[blockIdx.x] = sums[SCAN_TPB - 1];
}

__global__ void scan_b_kernel(int* __restrict__ partials, int nb) {
    if (blockIdx.x == 0 && threadIdx.x == 0) {
        int s = 0;
        for (int i = 0; i < nb; ++i) { int x = partials[i]; partials[i] = s; s += x; }
    }
}

__global__ __launch_bounds__(256) void scan_c_kernel(int* __restrict__ out,
                                                     const int* __restrict__ partials, int n) {
    int idx = blockIdx.x * blockDim.x + threadIdx.x;
    if (idx < n) out[idx] += partials[idx / SCAN_BE];
}

// ---- CSR fill: entry = {src, norm_bits} packed ----
__global__ __launch_bounds__(256) void csr_fill_kernel(const int* __restrict__ src,
                                                       const int* __restrict__ dst,
                                                       const int* __restrict__ rowptr,
                                                       int* __restrict__ cnt,
                                                       const float* __restrict__ disq,
                                                       int2* __restrict__ csr_ent, int E) {
    int e = blockIdx.x * blockDim.x + threadIdx.x;
    if (e >= E) return;
    int d = dst[e], s = src[e];
    int pos = rowptr[d] + atomicAdd(&cnt[d], 1);
    csr_ent[pos] = make_int2(s, __float_as_int(disq[s] * disq[d]));
}

// ---- weight prep: W[K][128] fp32 -> transposed, split, XOR-swizzled planes ----
__global__ __launch_bounds__(256) void prep_w_kernel(const float* __restrict__ W, int K,
                                                     unsigned short* __restrict__ planeHi,
                                                     unsigned short* __restrict__ planeLo) {
    int i = blockIdx.x * blockDim.x + threadIdx.x;
    if (i >= 128 * 128) return;
    int n = i >> 7, k = i & 127;
    float v = (k < K) ? W[k * 128 + n] : 0.0f;
    unsigned short hi, lo;
    split2(v, hi, lo);
    int elem = (n * 256 + ((2 * k) ^ ((n & 7) << 4))) >> 1;
    planeHi[elem] = hi;
    planeLo[elem] = lo;
}

// ---- x convert: [NN][78] fp32 -> hi/lo bf16 [NN][96] (zero pad) ----
__global__ __launch_bounds__(256) void xconv_kernel(const float* __restrict__ x,
                                                    unsigned short* __restrict__ xHi,
                                                    unsigned short* __restrict__ xLo) {
    long long t = (long long)blockIdx.x * blockDim.x + threadIdx.x;
    if (t >= (long long)NN * 96) return;
    int node = (int)(t / 96), k = (int)(t - (long long)node * 96);
    float v = (k < 78) ? x[(size_t)node * 78 + k] : 0.0f;
    unsigned short hi, lo;
    split2(v, hi, lo);
    size_t o = (size_t)node * 96 + k;
    xHi[o] = hi;
    xLo[o] = lo;
}

// ---- split-bf16 MFMA GEMM ----
template <int NKC, int AS>
__global__ __launch_bounds__(256) void gemm_mfma_kernel(const unsigned short* __restrict__ Ahi,
                                                        const unsigned short* __restrict__ Alo,
                                                        const unsigned short* __restrict__ WT,
                                                        float* __restrict__ C, int M) {
    __shared__ unsigned short lds[2 * 128 * 128];
    const int tid = threadIdx.x;
    {
        const unsigned* s = reinterpret_cast<const unsigned*>(WT);
        unsigned* d = reinterpret_cast<unsigned*>(lds);
#pragma unroll
        for (int i = 0; i < 64; ++i) d[tid + 256 * i] = s[tid + 256 * i];
    }
    __syncthreads();

    const int w = tid >> 6, lane = tid & 63;
    const int m = lane & 15, kb = lane >> 4;
    const char* ldsHiB = reinterpret_cast<const char*>(lds);
    const char* ldsLoB = ldsHiB + 128 * 256;

    const int RT = 4;
    for (int rt = 0; rt < RT; ++rt) {
        int row0 = (blockIdx.x * RT + rt) * 64;
        if (row0 >= M) return;
        int arow = row0 + w * 16 + m;

        bf16x8 ah[NKC], al[NKC];
#pragma unroll
        for (int kc = 0; kc < NKC; ++kc) {
            size_t off = (size_t)arow * AS + kc * 32 + kb * 8;
            ah[kc] = *reinterpret_cast<const bf16x8*>(Ahi + off);
            al[kc] = *reinterpret_cast<const bf16x8*>(Alo + off);
        }

        f32x4 acc[8];
#pragma unroll
        for (int ct = 0; ct < 8; ++ct)
#pragma unroll
            for (int r = 0; r < 4; ++r) acc[ct][r] = 0.0f;

#pragma unroll
        for (int ct = 0; ct < 8; ++ct) {
            int n = ct * 16 + m;
            int swz = (n & 7) << 4;
            int rowb = n * 256;
#pragma unroll
            for (int kc = 0; kc < NKC; ++kc) {
                int bb = rowb + ((kc * 64 + kb * 16) ^ swz);
                bf16x8 bh = *reinterpret_cast<const bf16x8*>(ldsHiB + bb);
                bf16x8 bl = *reinterpret_cast<const bf16x8*>(ldsLoB + bb);
                acc[ct] = __builtin_amdgcn_mfma_f32_16x16x32_bf16(ah[kc], bh, acc[ct], 0, 0, 0);
                acc[ct] = __builtin_amdgcn_mfma_f32_16x16x32_bf16(ah[kc], bl, acc[ct], 0, 0, 0);
                acc[ct] = __builtin_amdgcn_mfma_f32_16x16x32_bf16(al[kc], bh, acc[ct], 0, 0, 0);
            }
        }

        float* cp = C + (size_t)(row0 + w * 16) * 128;
#pragma unroll
        for (int ct = 0; ct < 8; ++ct)
#pragma unroll
            for (int r = 0; r < 4; ++r)
                cp[(size_t)(kb * 4 + r) * 128 + ct * 16 + m] = acc[ct][r];
    }
}

// ---- CSR gather with 4-wide predicated MLP ----
// 32 lanes per node. First 4 edges loaded in parallel (clamped index, zero
// norm for invalid slots) -> 4 independent gather chains; loop for deg>4.
__global__ __launch_bounds__(256) void gather_kernel(const float* __restrict__ h,
                                                     const int* __restrict__ rowptr,
                                                     const int* __restrict__ deg,
                                                     const int2* __restrict__ csr_ent,
                                                     const float* __restrict__ disq,
                                                     const float* __restrict__ bias,
                                                     unsigned short* __restrict__ outHi,
                                                     unsigned short* __restrict__ outLo, int n) {
    int t = blockIdx.x * blockDim.x + threadIdx.x;
    if (t >= n * 32) return;
    int node = t >> 5, q = (t & 31) * 4;
    int beg = rowptr[node];
    int d = deg[node];
    float si = disq[node];
    float s2 = si * si;
    float4 bv = *reinterpret_cast<const float4*>(bias + q);
    float4 hv = *reinterpret_cast<const float4*>(h + (size_t)node * 128 + q);
    float4 acc = make_float4(fmaf(hv.x, s2, bv.x), fmaf(hv.y, s2, bv.y),
                             fmaf(hv.z, s2, bv.z), fmaf(hv.w, s2, bv.w));
    if (d > 0) {
        int lim = d - 1;
        int2 e0 = csr_ent[beg];
        int2 e1 = csr_ent[beg + (1 < lim ? 1 : lim)];
        int2 e2 = csr_ent[beg + (2 < lim ? 2 : lim)];
        int2 e3 = csr_ent[beg + (3 < lim ? 3 : lim)];
        const float4* r0 = reinterpret_cast<const float4*>(h + (size_t)e0.x * 128 + q);
        const float4* r1 = reinterpret_cast<const float4*>(h + (size_t)e1.x * 128 + q);
        const float4* r2 = reinterpret_cast<const float4*>(h + (size_t)e2.x * 128 + q);
        const float4* r3 = reinterpret_cast<const float4*>(h + (size_t)e3.x * 128 + q);
        float4 v0 = *r0, v1 = *r1, v2 = *r2, v3 = *r3;
        float n0 = __int_as_float(e0.y);
        float n1 = (d > 1) ? __int_as_float(e1.y) : 0.0f;
        float n2 = (d > 2) ? __int_as_float(e2.y) : 0.0f;
        float n3 = (d > 3) ? __int_as_float(e3.y) : 0.0f;
        acc.x = fmaf(v0.x, n0, fmaf(v1.x, n1, fmaf(v2.x, n2, fmaf(v3.x, n3, acc.x))));
        acc.y = fmaf(v0.y, n0, fmaf(v1.y, n1, fmaf(v2.y, n2, fmaf(v3.y, n3, acc.y))));
        acc.z = fmaf(v0.z, n0, fmaf(v1.z, n1, fmaf(v2.z, n2, fmaf(v3.z, n3, acc.z))));
        acc.w = fmaf(v0.w, n0, fmaf(v1.w, n1, fmaf(v2.w, n2, fmaf(v3.w, n3, acc.w))));
        for (int j = 4; j < d; ++j) {
            int2 e = csr_ent[beg + j];
            float nr = __int_as_float(e.y);
            float4 v = *reinterpret_cast<const float4*>(h + (size_t)e.x * 128 + q);
            acc.x = fmaf(v.x, nr, acc.x);
            acc.y = fmaf(v.y, nr, acc.y);
            acc.z = fmaf(v.z, nr, acc.z);
            acc.w = fmaf(v.w, nr, acc.w);
        }
    }
    float av[4] = {fmaxf(acc.x, 0.f), fmaxf(acc.y, 0.f), fmaxf(acc.z, 0.f), fmaxf(acc.w, 0.f)};
    ushort4 h4, l4;
    split2(av[0], h4.x, l4.x);
    split2(av[1], h4.y, l4.y);
    split2(av[2], h4.z, l4.z);
    split2(av[3], h4.w, l4.w);
    size_t o = (size_t)node * 128 + q;
    *reinterpret_cast<ushort4*>(outHi + o) = h4;
    *reinterpret_cast<ushort4*>(outLo + o) = l4;
}

// fp32 VALU GEMM for the small FF head
template <bool RELU_A, bool EPI>
__global__ __launch_bounds__(256) void gemm_kernel(const float* __restrict__ A,
                                                   const float* __restrict__ B,
                                                   const float* __restrict__ bias,
                                                   float* __restrict__ C,
                                                   int M, int N, int K) {
    const int BM = 64, BN = 64, BK = 16;
    __shared__ float As[BK][BM + 4];
    __shared__ float Bs[BK][BN + 4];

    const int tid = threadIdx.x;
    const int bm = blockIdx.x * BM;
    const int bn = blockIdx.y * BN;
    const int tx = tid & 15;
    const int ty = tid >> 4;

    const int arow = tid >> 2;
    const int acol = (tid & 3) * 4;
    const int brow = tid >> 4;
    const int bcol = (tid & 15) * 4;

    float acc[4][4] = {};

    for (int k0 = 0; k0 < K; k0 += BK) {
        {
            const float* ap = A + (size_t)(bm + arow) * K;
#pragma unroll
            for (int j = 0; j < 4; ++j) {
                int kk = k0 + acol + j;
                float v = (kk < K) ? ap[kk] : 0.0f;
                if (RELU_A) v = fmaxf(v, 0.0f);
                As[acol + j][arow] = v;
            }
        }
        {
            int kk = k0 + brow;
            float4 v = make_float4(0.f, 0.f, 0.f, 0.f);
            if (kk < K) v = *reinterpret_cast<const float4*>(B + (size_t)kk * N + bn + bcol);
            *reinterpret_cast<float4*>(&Bs[brow][bcol]) = v;
        }
        __syncthreads();
#pragma unroll
        for (int k = 0; k < BK; ++k) {
            float4 a4 = *reinterpret_cast<const float4*>(&As[k][ty * 4]);
            float4 b4 = *reinterpret_cast<const float4*>(&Bs[k][tx * 4]);
            float av[4] = {a4.x, a4.y, a4.z, a4.w};
            float bv[4] = {b4.x, b4.y, b4.z, b4.w};
#pragma unroll
            for (int i = 0; i < 4; ++i)
#pragma unroll
                for (int j = 0; j < 4; ++j)
                    acc[i][j] = fmaf(av[i], bv[j], acc[i][j]);
        }
        __syncthreads();
    }

    const int crow0 = bm + ty * 4;
    const int ccol0 = bn + tx * 4;
    float4 bv = make_float4(0.f, 0.f, 0.f, 0.f);
    if (EPI) bv = *reinterpret_cast<const float4*>(bias + ccol0);
#pragma unroll
    for (int i = 0; i < 4; ++i) {
        float4 v = make_float4(acc[i][0], acc[i][1], acc[i][2], acc[i][3]);
        if (EPI) {
            v.x = fmaxf(v.x + bv.x, 0.f);
            v.y = fmaxf(v.y + bv.y, 0.f);
            v.z = fmaxf(v.z + bv.z, 0.f);
            v.w = fmaxf(v.w + bv.w, 0.f);
        }
        *reinterpret_cast<float4*>(C + (size_t)(crow0 + i) * N + ccol0) = v;
    }
}

// batch sorted: pre-reduce runs of 8 nodes, flush on boundary. reads hi/lo planes.
__global__ __launch_bounds__(256) void pool_kernel(const unsigned short* __restrict__ xHi,
                                                   const unsigned short* __restrict__ xLo,
                                                   const int* __restrict__ batch,
                                                   int* __restrict__ pooled, int n) {
    int t = blockIdx.x * blockDim.x + threadIdx.x;
    int d = t & 127;
    int n0 = (t >> 7) * 8;
    if (n0 >= n) return;
    int cur = batch[n0];
    size_t o = (size_t)n0 * 128 + d;
    float m = fmaxf(bf16_to_f(xHi[o]) + bf16_to_f(xLo[o]), 0.f);
    for (int i = 1; i < 8 && (n0 + i) < n; ++i) {
        int b = batch[n0 + i];
        size_t oi = (size_t)(n0 + i) * 128 + d;
        float v = fmaxf(bf16_to_f(xHi[oi]) + bf16_to_f(xLo[oi]), 0.f);
        if (b == cur) {
            m = fmaxf(m, v);
        } else {
            atomicMax(&pooled[cur * 128 + d], __float_as_int(m));
            cur = b;
            m = v;
        }
    }
    atomicMax(&pooled[cur * 128 + d], __float_as_int(m));
}

extern "C" void kernel_launch(void* const* d_in, const int* in_sizes, int n_in,
                              void* d_out, int out_size, void* d_ws, size_t ws_size,
                              hipStream_t stream) {
    const float* x    = (const float*)d_in[0];
    const int*   edge = (const int*)d_in[1];
    const int*   batch= (const int*)d_in[2];
    const float* gW0  = (const float*)d_in[4];
    const float* gb0  = (const float*)d_in[5];
    const float* gW1  = (const float*)d_in[6];
    const float* gb1  = (const float*)d_in[7];
    const float* gW2  = (const float*)d_in[8];
    const float* gb2  = (const float*)d_in[9];
    const float* fW0  = (const float*)d_in[10];
    const float* fb0  = (const float*)d_in[11];
    const float* fW1  = (const float*)d_in[12];
    const float* fb1  = (const float*)d_in[13];
    float* out = (float*)d_out;

    float* ws = (float*)d_ws;
    float* h = ws;                                            // NN*128 f32
    unsigned short* aggHi = (unsigned short*)(h + (size_t)NN * 128);
    unsigned short* aggLo = aggHi + (size_t)NN * 128;
    float* disq   = (float*)(aggLo + (size_t)NN * 128);       // NN
    float* pooled = disq + NN;                                // NG*128
    float* ffh    = pooled + (size_t)NG * 128;                // NG*256

    // aliases (disjoint lifetimes):
    int*   cnt      = (int*)pooled;              // dead before pool init
    int*   deg      = (int*)ffh;                 // ffh written only by FF head (last)
    int*   rowptr   = deg + NN;
    int2*  csr_ent  = (int2*)(rowptr + NN);                   // NE int2
    unsigned short* wt0 = (unsigned short*)(csr_ent + NE);    // 2*128*128 each
    unsigned short* wt1 = wt0 + 2 * 128 * 128;
    unsigned short* wt2 = wt1 + 2 * 128 * 128;
    int* partials = (int*)(wt2 + 2 * 128 * 128);              // ~200 ints
    unsigned short* xHi = aggHi;                 // x planes dead once h0 computed
    unsigned short* xLo = aggLo;

    const int* src = edge;
    const int* dst = edge + NE;

    // ---- degree + disq + CSR build + weight prep + x convert ----
    fill_int_kernel<<<cdiv(NN, 256), 256, 0, stream>>>(deg, 0, NN);
    fill_int_kernel<<<cdiv(NN, 256), 256, 0, stream>>>(cnt, 0, NN);
    hist_kernel<<<cdiv(NE, 256), 256, 0, stream>>>(dst, deg, NE);
    disq_kernel<<<cdiv(NN, 256), 256, 0, stream>>>(deg, disq, NN);
    int nsb = cdiv(NN, SCAN_BE);
    scan_a_kernel<<<nsb, SCAN_TPB, 0, stream>>>(deg, rowptr, partials, NN);
    scan_b_kernel<<<1, 64, 0, stream>>>(partials, nsb);
    scan_c_kernel<<<cdiv(NN, 256), 256, 0, stream>>>(rowptr, partials, NN);
    csr_fill_kernel<<<cdiv(NE, 256), 256, 0, stream>>>(src, dst, rowptr, cnt, disq,
                                                       csr_ent, NE);
    prep_w_kernel<<<64, 256, 0, stream>>>(gW0, 78, wt0, wt0 + 128 * 128);
    prep_w_kernel<<<64, 256, 0, stream>>>(gW1, 128, wt1, wt1 + 128 * 128);
    prep_w_kernel<<<64, 256, 0, stream>>>(gW2, 128, wt2, wt2 + 128 * 128);
    xconv_kernel<<<cdiv(NN * 96, 256), 256, 0, stream>>>(x, xHi, xLo);

    const int gemm_blocks = cdiv(NN / 64, 4);

    // ---- layer 0 ----
    gemm_mfma_kernel<3, 96><<<gemm_blocks, 256, 0, stream>>>(xHi, xLo, wt0, h, NN);
    gather_kernel<<<cdiv(NN * 32, 256), 256, 0, stream>>>(h, rowptr, deg, csr_ent,
                                                          disq, gb0, aggHi, aggLo, NN);
    // ---- layer 1 ----
    gemm_mfma_kernel<4, 128><<<gemm_blocks, 256, 0, stream>>>(aggHi, aggLo, wt1, h, NN);
    gather_kernel<<<cdiv(NN * 32, 256), 256, 0, stream>>>(h, rowptr, deg, csr_ent,
                                                          disq, gb1, aggHi, aggLo, NN);
    // ---- layer 2 ----
    gemm_mfma_kernel<4, 128><<<gemm_blocks, 256, 0, stream>>>(aggHi, aggLo, wt2, h, NN);
    gather_kernel<<<cdiv(NN * 32, 256), 256, 0, stream>>>(h, rowptr, deg, csr_ent,
                                                          disq, gb2, aggHi, aggLo, NN);

    // ---- global max pool (relu'd planes) ----
    fill_kernel<<<cdiv(NG * 128, 256), 256, 0, stream>>>(pooled, 0.0f, NG * 128);
    pool_kernel<<<cdiv(cdiv(NN, 8) * 128, 256), 256, 0, stream>>>(aggHi, aggLo, batch,
                                                                  (int*)pooled, NN);

    // ---- FF head (small, fp32 VALU) ----
    gemm_kernel<false, true><<<dim3(NG / 64, 4), 256, 0, stream>>>(pooled, fW0, fb0, ffh, NG, 256, 128);
    gemm_kernel<false, true><<<dim3(NG / 64, 2), 256, 0, stream>>>(ffh, fW1, fb1, out, NG, 128, 256);
}

// Round 5
// 839.672 us; speedup vs baseline: 6.0765x; 1.2462x over previous
//
#include <hip/hip_runtime.h>

#define NN 400000
#define NE 800000
#define NG 16384

typedef short bf16x8 __attribute__((ext_vector_type(8)));
typedef float f32x4 __attribute__((ext_vector_type(4)));

static inline int cdiv(int a, int b) { return (a + b - 1) / b; }

__device__ inline unsigned short bf16_rne(float v) {
    unsigned u = __float_as_uint(v);
    unsigned r = u + 0x7FFFu + ((u >> 16) & 1u);
    return (unsigned short)(r >> 16);
}
__device__ inline float bf16_to_f(unsigned short h) {
    return __uint_as_float(((unsigned)h) << 16);
}
__device__ inline void split2(float v, unsigned short& hi, unsigned short& lo) {
    hi = bf16_rne(v);
    lo = bf16_rne(v - bf16_to_f(hi));
}
__device__ inline float4 bf4_to_f4(ushort4 u) {
    return make_float4(bf16_to_f(u.x), bf16_to_f(u.y), bf16_to_f(u.z), bf16_to_f(u.w));
}

__global__ __launch_bounds__(256) void fill_kernel(float* __restrict__ p, float v, int n) {
    int i = blockIdx.x * blockDim.x + threadIdx.x;
    if (i < n) p[i] = v;
}

__global__ __launch_bounds__(256) void fill_int_kernel(int* __restrict__ p, int v, int n) {
    int i = blockIdx.x * blockDim.x + threadIdx.x;
    if (i < n) p[i] = v;
}

__global__ __launch_bounds__(256) void hist_kernel(const int* __restrict__ dst,
                                                   int* __restrict__ deg, int E) {
    int e = blockIdx.x * blockDim.x + threadIdx.x;
    if (e < E) atomicAdd(&deg[dst[e]], 1);
}

__global__ __launch_bounds__(256) void disq_kernel(const int* __restrict__ deg,
                                                   float* __restrict__ disq, int n) {
    int i = blockIdx.x * blockDim.x + threadIdx.x;
    if (i < n) disq[i] = rsqrtf(1.0f + (float)deg[i]);
}

// ---- 3-pass exclusive scan ----
#define SCAN_TPB 256
#define SCAN_EPT 8
#define SCAN_BE (SCAN_TPB * SCAN_EPT)

__global__ __launch_bounds__(SCAN_TPB) void scan_a_kernel(const int* __restrict__ in,
                                                          int* __restrict__ out,
                                                          int* __restrict__ partials, int n) {
    __shared__ int sums[SCAN_TPB];
    const int tid = threadIdx.x;
    int base = blockIdx.x * SCAN_BE + tid * SCAN_EPT;
    int v[SCAN_EPT];
    int s = 0;
#pragma unroll
    for (int i = 0; i < SCAN_EPT; ++i) {
        int idx = base + i;
        int x = (idx < n) ? in[idx] : 0;
        v[i] = s;
        s += x;
    }
    sums[tid] = s;
    __syncthreads();
    for (int off = 1; off < SCAN_TPB; off <<= 1) {
        int t = (tid >= off) ? sums[tid - off] : 0;
        __syncthreads();
        sums[tid] += t;
        __syncthreads();
    }
    int toff = (tid == 0) ? 0 : sums[tid - 1];
#pragma unroll
    for (int i = 0; i < SCAN_EPT; ++i) {
        int idx = base + i;
        if (idx < n) out[idx] = toff + v[i];
    }
    if (tid == SCAN_TPB - 1) partials[blockIdx.x] = sums[SCAN_TPB - 1];
}

__global__ void scan_b_kernel(int* __restrict__ partials, int nb) {
    if (blockIdx.x == 0 && threadIdx.x == 0) {
        int s = 0;
        for (int i = 0; i < nb; ++i) { int x = partials[i]; partials[i] = s; s += x; }
    }
}

__global__ __launch_bounds__(256) void scan_c_kernel(int* __restrict__ out,
                                                     const int* __restrict__ partials, int n) {
    int idx = blockIdx.x * blockDim.x + threadIdx.x;
    if (idx < n) out[idx] += partials[idx / SCAN_BE];
}

// ---- CSR fill: entry = {src, norm_bits} packed ----
__global__ __launch_bounds__(256) void csr_fill_kernel(const int* __restrict__ src,
                                                       const int* __restrict__ dst,
                                                       const int* __restrict__ rowptr,
                                                       int* __restrict__ cnt,
                                                       const float* __restrict__ disq,
                                                       int2* __restrict__ csr_ent, int E) {
    int e = blockIdx.x * blockDim.x + threadIdx.x;
    if (e >= E) return;
    int d = dst[e], s = src[e];
    int pos = rowptr[d] + atomicAdd(&cnt[d], 1);
    csr_ent[pos] = make_int2(s, __float_as_int(disq[s] * disq[d]));
}

// ---- weight prep: W[K][128] fp32 -> transposed, split, XOR-swizzled planes ----
__global__ __launch_bounds__(256) void prep_w_kernel(const float* __restrict__ W, int K,
                                                     unsigned short* __restrict__ planeHi,
                                                     unsigned short* __restrict__ planeLo) {
    int i = blockIdx.x * blockDim.x + threadIdx.x;
    if (i >= 128 * 128) return;
    int n = i >> 7, k = i & 127;
    float v = (k < K) ? W[k * 128 + n] : 0.0f;
    unsigned short hi, lo;
    split2(v, hi, lo);
    int elem = (n * 256 + ((2 * k) ^ ((n & 7) << 4))) >> 1;
    planeHi[elem] = hi;
    planeLo[elem] = lo;
}

// ---- x convert: [NN][78] fp32 -> bf16 hi-only [NN][96] (zero pad) ----
__global__ __launch_bounds__(256) void xconv_kernel(const float* __restrict__ x,
                                                    unsigned short* __restrict__ xbf) {
    long long t = (long long)blockIdx.x * blockDim.x + threadIdx.x;
    if (t >= (long long)NN * 96) return;
    int node = (int)(t / 96), k = (int)(t - (long long)node * 96);
    float v = (k < 78) ? x[(size_t)node * 78 + k] : 0.0f;
    xbf[(size_t)node * 96 + k] = bf16_rne(v);
}

// ---- CSR gather over bf16 activations: agg = act[i]*disq^2 + sum act[s]*norm ----
// 32 lanes/node, ushort4 per lane; fp32 accum, hi/lo split output.
// 4-wide predicated MLP for the first 4 edges, loop for deg>4.
template <int STRIDE>
__global__ __launch_bounds__(256) void gather_kernel(const unsigned short* __restrict__ act,
                                                     const int* __restrict__ rowptr,
                                                     const int* __restrict__ deg,
                                                     const int2* __restrict__ csr_ent,
                                                     const float* __restrict__ disq,
                                                     unsigned short* __restrict__ aggHi,
                                                     unsigned short* __restrict__ aggLo, int n) {
    int t = blockIdx.x * blockDim.x + threadIdx.x;
    if (t >= n * 32) return;
    int node = t >> 5, q = (t & 31) * 4;
    const bool live = q < STRIDE;
    const int qc = live ? q : 0;
    int beg = rowptr[node];
    int d = deg[node];
    float si = disq[node];
    float s2 = si * si;
    float4 sv = bf4_to_f4(*reinterpret_cast<const ushort4*>(act + (size_t)node * STRIDE + qc));
    float4 acc = make_float4(sv.x * s2, sv.y * s2, sv.z * s2, sv.w * s2);
    if (d > 0) {
        int lim = d - 1;
        int2 e0 = csr_ent[beg];
        int2 e1 = csr_ent[beg + (1 < lim ? 1 : lim)];
        int2 e2 = csr_ent[beg + (2 < lim ? 2 : lim)];
        int2 e3 = csr_ent[beg + (3 < lim ? 3 : lim)];
        ushort4 u0 = *reinterpret_cast<const ushort4*>(act + (size_t)e0.x * STRIDE + qc);
        ushort4 u1 = *reinterpret_cast<const ushort4*>(act + (size_t)e1.x * STRIDE + qc);
        ushort4 u2 = *reinterpret_cast<const ushort4*>(act + (size_t)e2.x * STRIDE + qc);
        ushort4 u3 = *reinterpret_cast<const ushort4*>(act + (size_t)e3.x * STRIDE + qc);
        float4 v0 = bf4_to_f4(u0), v1 = bf4_to_f4(u1), v2 = bf4_to_f4(u2), v3 = bf4_to_f4(u3);
        float n0 = __int_as_float(e0.y);
        float n1 = (d > 1) ? __int_as_float(e1.y) : 0.0f;
        float n2 = (d > 2) ? __int_as_float(e2.y) : 0.0f;
        float n3 = (d > 3) ? __int_as_float(e3.y) : 0.0f;
        acc.x = fmaf(v0.x, n0, fmaf(v1.x, n1, fmaf(v2.x, n2, fmaf(v3.x, n3, acc.x))));
        acc.y = fmaf(v0.y, n0, fmaf(v1.y, n1, fmaf(v2.y, n2, fmaf(v3.y, n3, acc.y))));
        acc.z = fmaf(v0.z, n0, fmaf(v1.z, n1, fmaf(v2.z, n2, fmaf(v3.z, n3, acc.z))));
        acc.w = fmaf(v0.w, n0, fmaf(v1.w, n1, fmaf(v2.w, n2, fmaf(v3.w, n3, acc.w))));
        for (int j = 4; j < d; ++j) {
            int2 e = csr_ent[beg + j];
            float nr = __int_as_float(e.y);
            float4 v = bf4_to_f4(*reinterpret_cast<const ushort4*>(act + (size_t)e.x * STRIDE + qc));
            acc.x = fmaf(v.x, nr, acc.x);
            acc.y = fmaf(v.y, nr, acc.y);
            acc.z = fmaf(v.z, nr, acc.z);
            acc.w = fmaf(v.w, nr, acc.w);
        }
    }
    if (live) {
        ushort4 h4, l4;
        split2(acc.x, h4.x, l4.x);
        split2(acc.y, h4.y, l4.y);
        split2(acc.z, h4.z, l4.z);
        split2(acc.w, h4.w, l4.w);
        size_t o = (size_t)node * STRIDE + q;
        *reinterpret_cast<ushort4*>(aggHi + o) = h4;
        *reinterpret_cast<ushort4*>(aggLo + o) = l4;
    }
}

// ---- split-bf16 MFMA GEMM with fused bias+relu+bf16 epilogue ----
// act[M,128] = relu((Ahi+Alo)[M,K(AS)] @ (Whi+Wlo)[K,128] + bias), bf16 hi-only.
template <int NKC, int AS>
__global__ __launch_bounds__(256) void gemm_mfma_kernel(const unsigned short* __restrict__ Ahi,
                                                        const unsigned short* __restrict__ Alo,
                                                        const unsigned short* __restrict__ WT,
                                                        const float* __restrict__ bias,
                                                        unsigned short* __restrict__ act, int M) {
    __shared__ unsigned short lds[2 * 128 * 128];
    const int tid = threadIdx.x;
    {
        const unsigned* s = reinterpret_cast<const unsigned*>(WT);
        unsigned* d = reinterpret_cast<unsigned*>(lds);
#pragma unroll
        for (int i = 0; i < 64; ++i) d[tid + 256 * i] = s[tid + 256 * i];
    }
    __syncthreads();

    const int w = tid >> 6, lane = tid & 63;
    const int m = lane & 15, kb = lane >> 4;
    const char* ldsHiB = reinterpret_cast<const char*>(lds);
    const char* ldsLoB = ldsHiB + 128 * 256;

    float bcol[8];
#pragma unroll
    for (int ct = 0; ct < 8; ++ct) bcol[ct] = bias[ct * 16 + m];

    const int RT = 4;
    for (int rt = 0; rt < RT; ++rt) {
        int row0 = (blockIdx.x * RT + rt) * 64;
        if (row0 >= M) return;
        int arow = row0 + w * 16 + m;

        bf16x8 ah[NKC], al[NKC];
#pragma unroll
        for (int kc = 0; kc < NKC; ++kc) {
            size_t off = (size_t)arow * AS + kc * 32 + kb * 8;
            ah[kc] = *reinterpret_cast<const bf16x8*>(Ahi + off);
            al[kc] = *reinterpret_cast<const bf16x8*>(Alo + off);
        }

        f32x4 acc[8];
#pragma unroll
        for (int ct = 0; ct < 8; ++ct)
#pragma unroll
            for (int r = 0; r < 4; ++r) acc[ct][r] = 0.0f;

#pragma unroll
        for (int ct = 0; ct < 8; ++ct) {
            int n = ct * 16 + m;
            int swz = (n & 7) << 4;
            int rowb = n * 256;
#pragma unroll
            for (int kc = 0; kc < NKC; ++kc) {
                int bb = rowb + ((kc * 64 + kb * 16) ^ swz);
                bf16x8 bh = *reinterpret_cast<const bf16x8*>(ldsHiB + bb);
                bf16x8 bl = *reinterpret_cast<const bf16x8*>(ldsLoB + bb);
                acc[ct] = __builtin_amdgcn_mfma_f32_16x16x32_bf16(ah[kc], bh, acc[ct], 0, 0, 0);
                acc[ct] = __builtin_amdgcn_mfma_f32_16x16x32_bf16(ah[kc], bl, acc[ct], 0, 0, 0);
                acc[ct] = __builtin_amdgcn_mfma_f32_16x16x32_bf16(al[kc], bh, acc[ct], 0, 0, 0);
            }
        }

        // C/D: col = ct*16 + (lane&15), row = (lane>>4)*4 + r   [m89]
        unsigned short* ap = act + (size_t)(row0 + w * 16) * 128;
#pragma unroll
        for (int ct = 0; ct < 8; ++ct)
#pragma unroll
            for (int r = 0; r < 4; ++r) {
                float v = fmaxf(acc[ct][r] + bcol[ct], 0.0f);
                ap[(size_t)(kb * 4 + r) * 128 + ct * 16 + m] = bf16_rne(v);
            }
    }
}

// fp32 VALU GEMM for the small FF head
template <bool RELU_A, bool EPI>
__global__ __launch_bounds__(256) void gemm_kernel(const float* __restrict__ A,
                                                   const float* __restrict__ B,
                                                   const float* __restrict__ bias,
                                                   float* __restrict__ C,
                                                   int M, int N, int K) {
    const int BM = 64, BN = 64, BK = 16;
    __shared__ float As[BK][BM + 4];
    __shared__ float Bs[BK][BN + 4];

    const int tid = threadIdx.x;
    const int bm = blockIdx.x * BM;
    const int bn = blockIdx.y * BN;
    const int tx = tid & 15;
    const int ty = tid >> 4;

    const int arow = tid >> 2;
    const int acol = (tid & 3) * 4;
    const int brow = tid >> 4;
    const int bcol = (tid & 15) * 4;

    float acc[4][4] = {};

    for (int k0 = 0; k0 < K; k0 += BK) {
        {
            const float* ap = A + (size_t)(bm + arow) * K;
#pragma unroll
            for (int j = 0; j < 4; ++j) {
                int kk = k0 + acol + j;
                float v = (kk < K) ? ap[kk] : 0.0f;
                if (RELU_A) v = fmaxf(v, 0.0f);
                As[acol + j][arow] = v;
            }
        }
        {
            int kk = k0 + brow;
            float4 v = make_float4(0.f, 0.f, 0.f, 0.f);
            if (kk < K) v = *reinterpret_cast<const float4*>(B + (size_t)kk * N + bn + bcol);
            *reinterpret_cast<float4*>(&Bs[brow][bcol]) = v;
        }
        __syncthreads();
#pragma unroll
        for (int k = 0; k < BK; ++k) {
            float4 a4 = *reinterpret_cast<const float4*>(&As[k][ty * 4]);
            float4 b4 = *reinterpret_cast<const float4*>(&Bs[k][tx * 4]);
            float av[4] = {a4.x, a4.y, a4.z, a4.w};
            float bv[4] = {b4.x, b4.y, b4.z, b4.w};
#pragma unroll
            for (int i = 0; i < 4; ++i)
#pragma unroll
                for (int j = 0; j < 4; ++j)
                    acc[i][j] = fmaf(av[i], bv[j], acc[i][j]);
        }
        __syncthreads();
    }

    const int crow0 = bm + ty * 4;
    const int ccol0 = bn + tx * 4;
    float4 bv = make_float4(0.f, 0.f, 0.f, 0.f);
    if (EPI) bv = *reinterpret_cast<const float4*>(bias + ccol0);
#pragma unroll
    for (int i = 0; i < 4; ++i) {
        float4 v = make_float4(acc[i][0], acc[i][1], acc[i][2], acc[i][3]);
        if (EPI) {
            v.x = fmaxf(v.x + bv.x, 0.f);
            v.y = fmaxf(v.y + bv.y, 0.f);
            v.z = fmaxf(v.z + bv.z, 0.f);
            v.w = fmaxf(v.w + bv.w, 0.f);
        }
        *reinterpret_cast<float4*>(C + (size_t)(crow0 + i) * N + ccol0) = v;
    }
}

// batch sorted: pre-reduce runs of 8 nodes, flush on boundary. reads bf16 act.
__global__ __launch_bounds__(256) void pool_kernel(const unsigned short* __restrict__ act,
                                                   const int* __restrict__ batch,
                                                   int* __restrict__ pooled, int n) {
    int t = blockIdx.x * blockDim.x + threadIdx.x;
    int d = t & 127;
    int n0 = (t >> 7) * 8;
    if (n0 >= n) return;
    int cur = batch[n0];
    float m = fmaxf(bf16_to_f(act[(size_t)n0 * 128 + d]), 0.f);
    for (int i = 1; i < 8 && (n0 + i) < n; ++i) {
        int b = batch[n0 + i];
        float v = fmaxf(bf16_to_f(act[(size_t)(n0 + i) * 128 + d]), 0.f);
        if (b == cur) {
            m = fmaxf(m, v);
        } else {
            atomicMax(&pooled[cur * 128 + d], __float_as_int(m));
            cur = b;
            m = v;
        }
    }
    atomicMax(&pooled[cur * 128 + d], __float_as_int(m));
}

extern "C" void kernel_launch(void* const* d_in, const int* in_sizes, int n_in,
                              void* d_out, int out_size, void* d_ws, size_t ws_size,
                              hipStream_t stream) {
    const float* x    = (const float*)d_in[0];
    const int*   edge = (const int*)d_in[1];
    const int*   batch= (const int*)d_in[2];
    const float* gW0  = (const float*)d_in[4];
    const float* gb0  = (const float*)d_in[5];
    const float* gW1  = (const float*)d_in[6];
    const float* gb1  = (const float*)d_in[7];
    const float* gW2  = (const float*)d_in[8];
    const float* gb2  = (const float*)d_in[9];
    const float* fW0  = (const float*)d_in[10];
    const float* fb0  = (const float*)d_in[11];
    const float* fW1  = (const float*)d_in[12];
    const float* fb1  = (const float*)d_in[13];
    float* out = (float*)d_out;

    unsigned short* actB  = (unsigned short*)d_ws;            // NN*128 bf16 (aliases xbf NN*96)
    unsigned short* aggHi = actB + (size_t)NN * 128;          // NN*128 bf16
    unsigned short* aggLo = aggHi + (size_t)NN * 128;         // NN*128 bf16
    float* disq   = (float*)(aggLo + (size_t)NN * 128);       // NN
    float* pooled = disq + NN;                                // NG*128
    float* ffh    = pooled + (size_t)NG * 128;                // NG*256
    int*   deg    = (int*)(ffh + (size_t)NG * 256);           // NN
    int*   rowptr = deg + NN;                                 // NN
    int2*  csr_ent = (int2*)(rowptr + NN);                    // NE
    unsigned short* wt0 = (unsigned short*)(csr_ent + NE);    // 2*128*128 each
    unsigned short* wt1 = wt0 + 2 * 128 * 128;
    unsigned short* wt2 = wt1 + 2 * 128 * 128;
    int* partials = (int*)(wt2 + 2 * 128 * 128);              // ~200 ints
    int* cnt = (int*)pooled;                                  // dead before pool init
    unsigned short* xbf = actB;                               // [NN,96] hi-only; dead after gather0

    const int* src = edge;
    const int* dst = edge + NE;

    // ---- degree + disq + CSR build + weight prep + x convert ----
    fill_int_kernel<<<cdiv(NN, 256), 256, 0, stream>>>(deg, 0, NN);
    fill_int_kernel<<<cdiv(NN, 256), 256, 0, stream>>>(cnt, 0, NN);
    hist_kernel<<<cdiv(NE, 256), 256, 0, stream>>>(dst, deg, NE);
    disq_kernel<<<cdiv(NN, 256), 256, 0, stream>>>(deg, disq, NN);
    int nsb = cdiv(NN, SCAN_BE);
    scan_a_kernel<<<nsb, SCAN_TPB, 0, stream>>>(deg, rowptr, partials, NN);
    scan_b_kernel<<<1, 64, 0, stream>>>(partials, nsb);
    scan_c_kernel<<<cdiv(NN, 256), 256, 0, stream>>>(rowptr, partials, NN);
    csr_fill_kernel<<<cdiv(NE, 256), 256, 0, stream>>>(src, dst, rowptr, cnt, disq,
                                                       csr_ent, NE);
    prep_w_kernel<<<64, 256, 0, stream>>>(gW0, 78, wt0, wt0 + 128 * 128);
    prep_w_kernel<<<64, 256, 0, stream>>>(gW1, 128, wt1, wt1 + 128 * 128);
    prep_w_kernel<<<64, 256, 0, stream>>>(gW2, 128, wt2, wt2 + 128 * 128);
    xconv_kernel<<<cdiv(NN * 96, 256), 256, 0, stream>>>(x, xbf);

    const int gemm_blocks = cdiv(NN / 64, 4);
    const int gather_blocks = cdiv(NN * 32, 256);

    // ---- layer 0: agg = A_hat x ; act = relu(agg@W0 + b0) ----
    gather_kernel<96><<<gather_blocks, 256, 0, stream>>>(xbf, rowptr, deg, csr_ent, disq,
                                                         aggHi, aggLo, NN);
    gemm_mfma_kernel<3, 96><<<gemm_blocks, 256, 0, stream>>>(aggHi, aggLo, wt0, gb0, actB, NN);
    // ---- layer 1 ----
    gather_kernel<128><<<gather_blocks, 256, 0, stream>>>(actB, rowptr, deg, csr_ent, disq,
                                                          aggHi, aggLo, NN);
    gemm_mfma_kernel<4, 128><<<gemm_blocks, 256, 0, stream>>>(aggHi, aggLo, wt1, gb1, actB, NN);
    // ---- layer 2 ----
    gather_kernel<128><<<gather_blocks, 256, 0, stream>>>(actB, rowptr, deg, csr_ent, disq,
                                                          aggHi, aggLo, NN);
    gemm_mfma_kernel<4, 128><<<gemm_blocks, 256, 0, stream>>>(aggHi, aggLo, wt2, gb2, actB, NN);

    // ---- global max pool ----
    fill_kernel<<<cdiv(NG * 128, 256), 256, 0, stream>>>(pooled, 0.0f, NG * 128);
    pool_kernel<<<cdiv(cdiv(NN, 8) * 128, 256), 256, 0, stream>>>(actB, batch, (int*)pooled, NN);

    // ---- FF head (small, fp32 VALU) ----
    gemm_kernel<false, true><<<dim3(NG / 64, 4), 256, 0, stream>>>(pooled, fW0, fb0, ffh, NG, 256, 128);
    gemm_kernel<false, true><<<dim3(NG / 64, 2), 256, 0, stream>>>(ffh, fW1, fb1, out, NG, 128, 256);
}

// Round 6
// 699.109 us; speedup vs baseline: 7.2982x; 1.2011x over previous
//
#include <hip/hip_runtime.h>

#define NN 400000
#define NE 800000
#define NG 16384

typedef short bf16x8 __attribute__((ext_vector_type(8)));
typedef float f32x4 __attribute__((ext_vector_type(4)));

static inline int cdiv(int a, int b) { return (a + b - 1) / b; }

__device__ inline unsigned short bf16_rne(float v) {
    unsigned u = __float_as_uint(v);
    unsigned r = u + 0x7FFFu + ((u >> 16) & 1u);
    return (unsigned short)(r >> 16);
}
__device__ inline float bf16_to_f(unsigned short h) {
    return __uint_as_float(((unsigned)h) << 16);
}
__device__ inline void split2(float v, unsigned short& hi, unsigned short& lo) {
    hi = bf16_rne(v);
    lo = bf16_rne(v - bf16_to_f(hi));
}
__device__ inline float4 bf4_to_f4(ushort4 u) {
    return make_float4(bf16_to_f(u.x), bf16_to_f(u.y), bf16_to_f(u.z), bf16_to_f(u.w));
}

__global__ __launch_bounds__(256) void fill_kernel(float* __restrict__ p, float v, int n) {
    int i = blockIdx.x * blockDim.x + threadIdx.x;
    if (i < n) p[i] = v;
}

__global__ __launch_bounds__(256) void fill_int_kernel(int* __restrict__ p, int v, int n) {
    int i = blockIdx.x * blockDim.x + threadIdx.x;
    if (i < n) p[i] = v;
}

__global__ __launch_bounds__(256) void hist_kernel(const int* __restrict__ dst,
                                                   int* __restrict__ deg, int E) {
    int e = blockIdx.x * blockDim.x + threadIdx.x;
    if (e < E) atomicAdd(&deg[dst[e]], 1);
}

__global__ __launch_bounds__(256) void disq_kernel(const int* __restrict__ deg,
                                                   float* __restrict__ disq, int n) {
    int i = blockIdx.x * blockDim.x + threadIdx.x;
    if (i < n) disq[i] = rsqrtf(1.0f + (float)deg[i]);
}

// ---- 3-pass exclusive scan ----
#define SCAN_TPB 256
#define SCAN_EPT 8
#define SCAN_BE (SCAN_TPB * SCAN_EPT)

__global__ __launch_bounds__(SCAN_TPB) void scan_a_kernel(const int* __restrict__ in,
                                                          int* __restrict__ out,
                                                          int* __restrict__ partials, int n) {
    __shared__ int sums[SCAN_TPB];
    const int tid = threadIdx.x;
    int base = blockIdx.x * SCAN_BE + tid * SCAN_EPT;
    int v[SCAN_EPT];
    int s = 0;
#pragma unroll
    for (int i = 0; i < SCAN_EPT; ++i) {
        int idx = base + i;
        int x = (idx < n) ? in[idx] : 0;
        v[i] = s;
        s += x;
    }
    sums[tid] = s;
    __syncthreads();
    for (int off = 1; off < SCAN_TPB; off <<= 1) {
        int t = (tid >= off) ? sums[tid - off] : 0;
        __syncthreads();
        sums[tid] += t;
        __syncthreads();
    }
    int toff = (tid == 0) ? 0 : sums[tid - 1];
#pragma unroll
    for (int i = 0; i < SCAN_EPT; ++i) {
        int idx = base + i;
        if (idx < n) out[idx] = toff + v[i];
    }
    if (tid == SCAN_TPB - 1) partials[blockIdx.x] = sums[SCAN_TPB - 1];
}

__global__ void scan_b_kernel(int* __restrict__ partials, int nb) {
    if (blockIdx.x == 0 && threadIdx.x == 0) {
        int s = 0;
        for (int i = 0; i < nb; ++i) { int x = partials[i]; partials[i] = s; s += x; }
    }
}

__global__ __launch_bounds__(256) void scan_c_kernel(int* __restrict__ out,
                                                     const int* __restrict__ partials, int n) {
    int idx = blockIdx.x * blockDim.x + threadIdx.x;
    if (idx < n) out[idx] += partials[idx / SCAN_BE];
}

// ---- CSR fill: entry = {src, norm_bits} packed ----
__global__ __launch_bounds__(256) void csr_fill_kernel(const int* __restrict__ src,
                                                       const int* __restrict__ dst,
                                                       const int* __restrict__ rowptr,
                                                       int* __restrict__ cnt,
                                                       const float* __restrict__ disq,
                                                       int2* __restrict__ csr_ent, int E) {
    int e = blockIdx.x * blockDim.x + threadIdx.x;
    if (e >= E) return;
    int d = dst[e], s = src[e];
    int pos = rowptr[d] + atomicAdd(&cnt[d], 1);
    csr_ent[pos] = make_int2(s, __float_as_int(disq[s] * disq[d]));
}

// ---- weight prep: W[K][128] fp32 -> transposed, split, XOR-swizzled planes ----
__global__ __launch_bounds__(256) void prep_w_kernel(const float* __restrict__ W, int K,
                                                     unsigned short* __restrict__ planeHi,
                                                     unsigned short* __restrict__ planeLo) {
    int i = blockIdx.x * blockDim.x + threadIdx.x;
    if (i >= 128 * 128) return;
    int n = i >> 7, k = i & 127;
    float v = (k < K) ? W[k * 128 + n] : 0.0f;
    unsigned short hi, lo;
    split2(v, hi, lo);
    int elem = (n * 256 + ((2 * k) ^ ((n & 7) << 4))) >> 1;
    planeHi[elem] = hi;
    planeLo[elem] = lo;
}

// ---- x convert: [NN][78] fp32 -> bf16 hi-only [NN][96] (zero pad) ----
__global__ __launch_bounds__(256) void xconv_kernel(const float* __restrict__ x,
                                                    unsigned short* __restrict__ xbf) {
    long long t = (long long)blockIdx.x * blockDim.x + threadIdx.x;
    if (t >= (long long)NN * 96) return;
    int node = (int)(t / 96), k = (int)(t - (long long)node * 96);
    float v = (k < 78) ? x[(size_t)node * 78 + k] : 0.0f;
    xbf[(size_t)node * 96 + k] = bf16_rne(v);
}

// ---- CSR gather over bf16 activations -> bf16 hi-only agg ----
// 32 lanes/node, ushort4 per lane; fp32 accum.
// 6-wide predicated MLP for the first 6 edges, loop for deg>6.
template <int STRIDE>
__global__ __launch_bounds__(256) void gather_kernel(const unsigned short* __restrict__ act,
                                                     const int* __restrict__ rowptr,
                                                     const int* __restrict__ deg,
                                                     const int2* __restrict__ csr_ent,
                                                     const float* __restrict__ disq,
                                                     unsigned short* __restrict__ aggHi, int n) {
    int t = blockIdx.x * blockDim.x + threadIdx.x;
    if (t >= n * 32) return;
    int node = t >> 5, q = (t & 31) * 4;
    const bool live = q < STRIDE;
    const int qc = live ? q : 0;
    int beg = rowptr[node];
    int d = deg[node];
    float si = disq[node];
    float s2 = si * si;
    float4 sv = bf4_to_f4(*reinterpret_cast<const ushort4*>(act + (size_t)node * STRIDE + qc));
    float4 acc = make_float4(sv.x * s2, sv.y * s2, sv.z * s2, sv.w * s2);
    if (d > 0) {
        int lim = d - 1;
        int2 e[6];
#pragma unroll
        for (int j = 0; j < 6; ++j) e[j] = csr_ent[beg + (j < lim ? j : lim)];
        float4 v[6];
        float nr[6];
#pragma unroll
        for (int j = 0; j < 6; ++j) {
            v[j] = bf4_to_f4(*reinterpret_cast<const ushort4*>(act + (size_t)e[j].x * STRIDE + qc));
            nr[j] = (j < d) ? __int_as_float(e[j].y) : 0.0f;
        }
#pragma unroll
        for (int j = 0; j < 6; ++j) {
            acc.x = fmaf(v[j].x, nr[j], acc.x);
            acc.y = fmaf(v[j].y, nr[j], acc.y);
            acc.z = fmaf(v[j].z, nr[j], acc.z);
            acc.w = fmaf(v[j].w, nr[j], acc.w);
        }
        for (int j = 6; j < d; ++j) {
            int2 ee = csr_ent[beg + j];
            float nn = __int_as_float(ee.y);
            float4 vv = bf4_to_f4(*reinterpret_cast<const ushort4*>(act + (size_t)ee.x * STRIDE + qc));
            acc.x = fmaf(vv.x, nn, acc.x);
            acc.y = fmaf(vv.y, nn, acc.y);
            acc.z = fmaf(vv.z, nn, acc.z);
            acc.w = fmaf(vv.w, nn, acc.w);
        }
    }
    if (live) {
        ushort4 h4;
        h4.x = bf16_rne(acc.x);
        h4.y = bf16_rne(acc.y);
        h4.z = bf16_rne(acc.z);
        h4.w = bf16_rne(acc.w);
        *reinterpret_cast<ushort4*>(aggHi + (size_t)node * STRIDE + q) = h4;
    }
}

// ---- bf16 MFMA GEMM, split weights: act = relu(A @ (Whi+Wlo) + bias) ----
// A bf16 [M, AS]; WT planes swizzled [128][128]; output bf16 hi-only.
template <int NKC, int AS>
__global__ __launch_bounds__(256) void gemm_mfma_kernel(const unsigned short* __restrict__ A,
                                                        const unsigned short* __restrict__ WT,
                                                        const float* __restrict__ bias,
                                                        unsigned short* __restrict__ act, int M) {
    __shared__ unsigned short lds[2 * 128 * 128];
    const int tid = threadIdx.x;
    {
        const unsigned* s = reinterpret_cast<const unsigned*>(WT);
        unsigned* d = reinterpret_cast<unsigned*>(lds);
#pragma unroll
        for (int i = 0; i < 64; ++i) d[tid + 256 * i] = s[tid + 256 * i];
    }
    __syncthreads();

    const int w = tid >> 6, lane = tid & 63;
    const int m = lane & 15, kb = lane >> 4;
    const char* ldsHiB = reinterpret_cast<const char*>(lds);
    const char* ldsLoB = ldsHiB + 128 * 256;

    float bcol[8];
#pragma unroll
    for (int ct = 0; ct < 8; ++ct) bcol[ct] = bias[ct * 16 + m];

    const int RT = 4;
    for (int rt = 0; rt < RT; ++rt) {
        int row0 = (blockIdx.x * RT + rt) * 64;
        if (row0 >= M) return;
        int arow = row0 + w * 16 + m;

        bf16x8 ah[NKC];
#pragma unroll
        for (int kc = 0; kc < NKC; ++kc)
            ah[kc] = *reinterpret_cast<const bf16x8*>(A + (size_t)arow * AS + kc * 32 + kb * 8);

        f32x4 acc[8];
#pragma unroll
        for (int ct = 0; ct < 8; ++ct)
#pragma unroll
            for (int r = 0; r < 4; ++r) acc[ct][r] = 0.0f;

#pragma unroll
        for (int ct = 0; ct < 8; ++ct) {
            int n = ct * 16 + m;
            int swz = (n & 7) << 4;
            int rowb = n * 256;
#pragma unroll
            for (int kc = 0; kc < NKC; ++kc) {
                int bb = rowb + ((kc * 64 + kb * 16) ^ swz);
                bf16x8 bh = *reinterpret_cast<const bf16x8*>(ldsHiB + bb);
                bf16x8 bl = *reinterpret_cast<const bf16x8*>(ldsLoB + bb);
                acc[ct] = __builtin_amdgcn_mfma_f32_16x16x32_bf16(ah[kc], bh, acc[ct], 0, 0, 0);
                acc[ct] = __builtin_amdgcn_mfma_f32_16x16x32_bf16(ah[kc], bl, acc[ct], 0, 0, 0);
            }
        }

        // C/D: col = ct*16 + (lane&15), row = (lane>>4)*4 + r   [m89]
        unsigned short* ap = act + (size_t)(row0 + w * 16) * 128;
#pragma unroll
        for (int ct = 0; ct < 8; ++ct)
#pragma unroll
            for (int r = 0; r < 4; ++r) {
                float v = fmaxf(acc[ct][r] + bcol[ct], 0.0f);
                ap[(size_t)(kb * 4 + r) * 128 + ct * 16 + m] = bf16_rne(v);
            }
    }
}

// fp32 VALU GEMM for the small FF head
template <bool RELU_A, bool EPI>
__global__ __launch_bounds__(256) void gemm_kernel(const float* __restrict__ A,
                                                   const float* __restrict__ B,
                                                   const float* __restrict__ bias,
                                                   float* __restrict__ C,
                                                   int M, int N, int K) {
    const int BM = 64, BN = 64, BK = 16;
    __shared__ float As[BK][BM + 4];
    __shared__ float Bs[BK][BN + 4];

    const int tid = threadIdx.x;
    const int bm = blockIdx.x * BM;
    const int bn = blockIdx.y * BN;
    const int tx = tid & 15;
    const int ty = tid >> 4;

    const int arow = tid >> 2;
    const int acol = (tid & 3) * 4;
    const int brow = tid >> 4;
    const int bcol = (tid & 15) * 4;

    float acc[4][4] = {};

    for (int k0 = 0; k0 < K; k0 += BK) {
        {
            const float* ap = A + (size_t)(bm + arow) * K;
#pragma unroll
            for (int j = 0; j < 4; ++j) {
                int kk = k0 + acol + j;
                float v = (kk < K) ? ap[kk] : 0.0f;
                if (RELU_A) v = fmaxf(v, 0.0f);
                As[acol + j][arow] = v;
            }
        }
        {
            int kk = k0 + brow;
            float4 v = make_float4(0.f, 0.f, 0.f, 0.f);
            if (kk < K) v = *reinterpret_cast<const float4*>(B + (size_t)kk * N + bn + bcol);
            *reinterpret_cast<float4*>(&Bs[brow][bcol]) = v;
        }
        __syncthreads();
#pragma unroll
        for (int k = 0; k < BK; ++k) {
            float4 a4 = *reinterpret_cast<const float4*>(&As[k][ty * 4]);
            float4 b4 = *reinterpret_cast<const float4*>(&Bs[k][tx * 4]);
            float av[4] = {a4.x, a4.y, a4.z, a4.w};
            float bv[4] = {b4.x, b4.y, b4.z, b4.w};
#pragma unroll
            for (int i = 0; i < 4; ++i)
#pragma unroll
                for (int j = 0; j < 4; ++j)
                    acc[i][j] = fmaf(av[i], bv[j], acc[i][j]);
        }
        __syncthreads();
    }

    const int crow0 = bm + ty * 4;
    const int ccol0 = bn + tx * 4;
    float4 bv = make_float4(0.f, 0.f, 0.f, 0.f);
    if (EPI) bv = *reinterpret_cast<const float4*>(bias + ccol0);
#pragma unroll
    for (int i = 0; i < 4; ++i) {
        float4 v = make_float4(acc[i][0], acc[i][1], acc[i][2], acc[i][3]);
        if (EPI) {
            v.x = fmaxf(v.x + bv.x, 0.f);
            v.y = fmaxf(v.y + bv.y, 0.f);
            v.z = fmaxf(v.z + bv.z, 0.f);
            v.w = fmaxf(v.w + bv.w, 0.f);
        }
        *reinterpret_cast<float4*>(C + (size_t)(crow0 + i) * N + ccol0) = v;
    }
}

// batch sorted: pre-reduce runs of 8 nodes, flush on boundary. reads bf16 act.
__global__ __launch_bounds__(256) void pool_kernel(const unsigned short* __restrict__ act,
                                                   const int* __restrict__ batch,
                                                   int* __restrict__ pooled, int n) {
    int t = blockIdx.x * blockDim.x + threadIdx.x;
    int d = t & 127;
    int n0 = (t >> 7) * 8;
    if (n0 >= n) return;
    int cur = batch[n0];
    float m = fmaxf(bf16_to_f(act[(size_t)n0 * 128 + d]), 0.f);
    for (int i = 1; i < 8 && (n0 + i) < n; ++i) {
        int b = batch[n0 + i];
        float v = fmaxf(bf16_to_f(act[(size_t)(n0 + i) * 128 + d]), 0.f);
        if (b == cur) {
            m = fmaxf(m, v);
        } else {
            atomicMax(&pooled[cur * 128 + d], __float_as_int(m));
            cur = b;
            m = v;
        }
    }
    atomicMax(&pooled[cur * 128 + d], __float_as_int(m));
}

extern "C" void kernel_launch(void* const* d_in, const int* in_sizes, int n_in,
                              void* d_out, int out_size, void* d_ws, size_t ws_size,
                              hipStream_t stream) {
    const float* x    = (const float*)d_in[0];
    const int*   edge = (const int*)d_in[1];
    const int*   batch= (const int*)d_in[2];
    const float* gW0  = (const float*)d_in[4];
    const float* gb0  = (const float*)d_in[5];
    const float* gW1  = (const float*)d_in[6];
    const float* gb1  = (const float*)d_in[7];
    const float* gW2  = (const float*)d_in[8];
    const float* gb2  = (const float*)d_in[9];
    const float* fW0  = (const float*)d_in[10];
    const float* fb0  = (const float*)d_in[11];
    const float* fW1  = (const float*)d_in[12];
    const float* fb1  = (const float*)d_in[13];
    float* out = (float*)d_out;

    unsigned short* actB  = (unsigned short*)d_ws;            // NN*128 bf16 (aliases xbf NN*96)
    unsigned short* aggHi = actB + (size_t)NN * 128;          // NN*128 bf16
    float* disq   = (float*)(aggHi + (size_t)NN * 128);       // NN
    float* pooled = disq + NN;                                // NG*128
    float* ffh    = pooled + (size_t)NG * 128;                // NG*256
    int*   deg    = (int*)(ffh + (size_t)NG * 256);           // NN
    int*   rowptr = deg + NN;                                 // NN
    int2*  csr_ent = (int2*)(rowptr + NN);                    // NE
    unsigned short* wt0 = (unsigned short*)(csr_ent + NE);    // 2*128*128 each
    unsigned short* wt1 = wt0 + 2 * 128 * 128;
    unsigned short* wt2 = wt1 + 2 * 128 * 128;
    int* partials = (int*)(wt2 + 2 * 128 * 128);              // ~200 ints
    int* cnt = (int*)pooled;                                  // dead before pool init
    unsigned short* xbf = actB;                               // [NN,96] hi-only; dead after gather0

    const int* src = edge;
    const int* dst = edge + NE;

    // ---- degree + disq + CSR build + weight prep + x convert ----
    fill_int_kernel<<<cdiv(NN, 256), 256, 0, stream>>>(deg, 0, NN);
    fill_int_kernel<<<cdiv(NN, 256), 256, 0, stream>>>(cnt, 0, NN);
    hist_kernel<<<cdiv(NE, 256), 256, 0, stream>>>(dst, deg, NE);
    disq_kernel<<<cdiv(NN, 256), 256, 0, stream>>>(deg, disq, NN);
    int nsb = cdiv(NN, SCAN_BE);
    scan_a_kernel<<<nsb, SCAN_TPB, 0, stream>>>(deg, rowptr, partials, NN);
    scan_b_kernel<<<1, 64, 0, stream>>>(partials, nsb);
    scan_c_kernel<<<cdiv(NN, 256), 256, 0, stream>>>(rowptr, partials, NN);
    csr_fill_kernel<<<cdiv(NE, 256), 256, 0, stream>>>(src, dst, rowptr, cnt, disq,
                                                       csr_ent, NE);
    prep_w_kernel<<<64, 256, 0, stream>>>(gW0, 78, wt0, wt0 + 128 * 128);
    prep_w_kernel<<<64, 256, 0, stream>>>(gW1, 128, wt1, wt1 + 128 * 128);
    prep_w_kernel<<<64, 256, 0, stream>>>(gW2, 128, wt2, wt2 + 128 * 128);
    xconv_kernel<<<cdiv(NN * 96, 256), 256, 0, stream>>>(x, xbf);

    const int gemm_blocks = cdiv(NN / 64, 4);
    const int gather_blocks = cdiv(NN * 32, 256);

    // ---- layer 0: agg = A_hat x ; act = relu(agg@W0 + b0) ----
    gather_kernel<96><<<gather_blocks, 256, 0, stream>>>(xbf, rowptr, deg, csr_ent, disq,
                                                         aggHi, NN);
    gemm_mfma_kernel<3, 96><<<gemm_blocks, 256, 0, stream>>>(aggHi, wt0, gb0, actB, NN);
    // ---- layer 1 ----
    gather_kernel<128><<<gather_blocks, 256, 0, stream>>>(actB, rowptr, deg, csr_ent, disq,
                                                          aggHi, NN);
    gemm_mfma_kernel<4, 128><<<gemm_blocks, 256, 0, stream>>>(aggHi, wt1, gb1, actB, NN);
    // ---- layer 2 ----
    gather_kernel<128><<<gather_blocks, 256, 0, stream>>>(actB, rowptr, deg, csr_ent, disq,
                                                          aggHi, NN);
    gemm_mfma_kernel<4, 128><<<gemm_blocks, 256, 0, stream>>>(aggHi, wt2, gb2, actB, NN);

    // ---- global max pool ----
    fill_kernel<<<cdiv(NG * 128, 256), 256, 0, stream>>>(pooled, 0.0f, NG * 128);
    pool_kernel<<<cdiv(cdiv(NN, 8) * 128, 256), 256, 0, stream>>>(actB, batch, (int*)pooled, NN);

    // ---- FF head (small, fp32 VALU) ----
    gemm_kernel<false, true><<<dim3(NG / 64, 4), 256, 0, stream>>>(pooled, fW0, fb0, ffh, NG, 256, 128);
    gemm_kernel<false, true><<<dim3(NG / 64, 2), 256, 0, stream>>>(ffh, fW1, fb1, out, NG, 128, 256);
}

// Round 7
// 627.521 us; speedup vs baseline: 8.1308x; 1.1141x over previous
//
#include <hip/hip_runtime.h>

#define NN 400000
#define NE 800000
#define NG 16384

typedef short bf16x8 __attribute__((ext_vector_type(8)));
typedef float f32x4 __attribute__((ext_vector_type(4)));
typedef unsigned short u16x8 __attribute__((ext_vector_type(8)));

static inline int cdiv(int a, int b) { return (a + b - 1) / b; }

__device__ inline unsigned short bf16_rne(float v) {
    unsigned u = __float_as_uint(v);
    unsigned r = u + 0x7FFFu + ((u >> 16) & 1u);
    return (unsigned short)(r >> 16);
}
__device__ inline float bf16_to_f(unsigned short h) {
    return __uint_as_float(((unsigned)h) << 16);
}
__device__ inline void split2(float v, unsigned short& hi, unsigned short& lo) {
    hi = bf16_rne(v);
    lo = bf16_rne(v - bf16_to_f(hi));
}

__global__ __launch_bounds__(256) void fill_kernel(float* __restrict__ p, float v, int n) {
    int i = blockIdx.x * blockDim.x + threadIdx.x;
    if (i < n) p[i] = v;
}

__global__ __launch_bounds__(256) void fill_int_kernel(int* __restrict__ p, int v, int n) {
    int i = blockIdx.x * blockDim.x + threadIdx.x;
    if (i < n) p[i] = v;
}

__global__ __launch_bounds__(256) void hist_kernel(const int* __restrict__ dst,
                                                   int* __restrict__ deg, int E) {
    int e = blockIdx.x * blockDim.x + threadIdx.x;
    if (e < E) atomicAdd(&deg[dst[e]], 1);
}

__global__ __launch_bounds__(256) void disq_kernel(const int* __restrict__ deg,
                                                   float* __restrict__ disq, int n) {
    int i = blockIdx.x * blockDim.x + threadIdx.x;
    if (i < n) disq[i] = rsqrtf(1.0f + (float)deg[i]);
}

// ---- 3-pass exclusive scan ----
#define SCAN_TPB 256
#define SCAN_EPT 8
#define SCAN_BE (SCAN_TPB * SCAN_EPT)

__global__ __launch_bounds__(SCAN_TPB) void scan_a_kernel(const int* __restrict__ in,
                                                          int* __restrict__ out,
                                                          int* __restrict__ partials, int n) {
    __shared__ int sums[SCAN_TPB];
    const int tid = threadIdx.x;
    int base = blockIdx.x * SCAN_BE + tid * SCAN_EPT;
    int v[SCAN_EPT];
    int s = 0;
#pragma unroll
    for (int i = 0; i < SCAN_EPT; ++i) {
        int idx = base + i;
        int x = (idx < n) ? in[idx] : 0;
        v[i] = s;
        s += x;
    }
    sums[tid] = s;
    __syncthreads();
    for (int off = 1; off < SCAN_TPB; off <<= 1) {
        int t = (tid >= off) ? sums[tid - off] : 0;
        __syncthreads();
        sums[tid] += t;
        __syncthreads();
    }
    int toff = (tid == 0) ? 0 : sums[tid - 1];
#pragma unroll
    for (int i = 0; i < SCAN_EPT; ++i) {
        int idx = base + i;
        if (idx < n) out[idx] = toff + v[i];
    }
    if (tid == SCAN_TPB - 1) partials[blockIdx.x] = sums[SCAN_TPB - 1];
}

__global__ void scan_b_kernel(int* __restrict__ partials, int nb) {
    if (blockIdx.x == 0 && threadIdx.x == 0) {
        int s = 0;
        for (int i = 0; i < nb; ++i) { int x = partials[i]; partials[i] = s; s += x; }
    }
}

__global__ __launch_bounds__(256) void scan_c_kernel(int* __restrict__ out,
                                                     const int* __restrict__ partials, int n) {
    int idx = blockIdx.x * blockDim.x + threadIdx.x;
    if (idx < n) out[idx] += partials[idx / SCAN_BE];
}

// ---- CSR fill: entry = {src, norm_bits} packed ----
__global__ __launch_bounds__(256) void csr_fill_kernel(const int* __restrict__ src,
                                                       const int* __restrict__ dst,
                                                       const int* __restrict__ rowptr,
                                                       int* __restrict__ cnt,
                                                       const float* __restrict__ disq,
                                                       int2* __restrict__ csr_ent, int E) {
    int e = blockIdx.x * blockDim.x + threadIdx.x;
    if (e >= E) return;
    int d = dst[e], s = src[e];
    int pos = rowptr[d] + atomicAdd(&cnt[d], 1);
    csr_ent[pos] = make_int2(s, __float_as_int(disq[s] * disq[d]));
}

// ---- weight prep: W[K][128] fp32 -> transposed, split, XOR-swizzled planes ----
__global__ __launch_bounds__(256) void prep_w_kernel(const float* __restrict__ W, int K,
                                                     unsigned short* __restrict__ planeHi,
                                                     unsigned short* __restrict__ planeLo) {
    int i = blockIdx.x * blockDim.x + threadIdx.x;
    if (i >= 128 * 128) return;
    int n = i >> 7, k = i & 127;
    float v = (k < K) ? W[k * 128 + n] : 0.0f;
    unsigned short hi, lo;
    split2(v, hi, lo);
    int elem = (n * 256 + ((2 * k) ^ ((n & 7) << 4))) >> 1;
    planeHi[elem] = hi;
    planeLo[elem] = lo;
}

// ---- x convert: [NN][78] fp32 -> bf16 hi-only [NN][96] (zero pad) ----
__global__ __launch_bounds__(256) void xconv_kernel(const float* __restrict__ x,
                                                    unsigned short* __restrict__ xbf) {
    long long t = (long long)blockIdx.x * blockDim.x + threadIdx.x;
    if (t >= (long long)NN * 96) return;
    int node = (int)(t / 96), k = (int)(t - (long long)node * 96);
    float v = (k < 78) ? x[(size_t)node * 78 + k] : 0.0f;
    xbf[(size_t)node * 96 + k] = bf16_rne(v);
}

// ---- CSR gather over bf16 activations -> bf16 hi-only agg ----
// 16 lanes/node, ushort8 (16B) per lane -> 4 independent node chains per wave.
// fp32 accum; 6-wide predicated MLP, loop for deg>6.
template <int STRIDE>
__global__ __launch_bounds__(256) void gather_kernel(const unsigned short* __restrict__ act,
                                                     const int* __restrict__ rowptr,
                                                     const int* __restrict__ deg,
                                                     const int2* __restrict__ csr_ent,
                                                     const float* __restrict__ disq,
                                                     unsigned short* __restrict__ aggHi, int n) {
    int t = blockIdx.x * blockDim.x + threadIdx.x;
    if (t >= n * 16) return;
    int node = t >> 4, q = (t & 15) * 8;
    const bool live = q < STRIDE;
    const int qc = live ? q : 0;
    int beg = rowptr[node];
    int d = deg[node];
    float si = disq[node];
    float s2 = si * si;
    u16x8 su = *reinterpret_cast<const u16x8*>(act + (size_t)node * STRIDE + qc);
    float acc[8];
#pragma unroll
    for (int i = 0; i < 8; ++i) acc[i] = bf16_to_f(su[i]) * s2;
    if (d > 0) {
        int lim = d - 1;
        int2 e[6];
#pragma unroll
        for (int j = 0; j < 6; ++j) e[j] = csr_ent[beg + (j < lim ? j : lim)];
        u16x8 u[6];
        float nr[6];
#pragma unroll
        for (int j = 0; j < 6; ++j) {
            u[j] = *reinterpret_cast<const u16x8*>(act + (size_t)e[j].x * STRIDE + qc);
            nr[j] = (j < d) ? __int_as_float(e[j].y) : 0.0f;
        }
#pragma unroll
        for (int j = 0; j < 6; ++j)
#pragma unroll
            for (int i = 0; i < 8; ++i) acc[i] = fmaf(bf16_to_f(u[j][i]), nr[j], acc[i]);
        for (int j = 6; j < d; ++j) {
            int2 ee = csr_ent[beg + j];
            float nn = __int_as_float(ee.y);
            u16x8 uu = *reinterpret_cast<const u16x8*>(act + (size_t)ee.x * STRIDE + qc);
#pragma unroll
            for (int i = 0; i < 8; ++i) acc[i] = fmaf(bf16_to_f(uu[i]), nn, acc[i]);
        }
    }
    if (live) {
        u16x8 h8;
#pragma unroll
        for (int i = 0; i < 8; ++i) h8[i] = bf16_rne(acc[i]);
        *reinterpret_cast<u16x8*>(aggHi + (size_t)node * STRIDE + q) = h8;
    }
}

// ---- bf16 MFMA GEMM, split weights: act = relu(A @ (Whi+Wlo) + bias) ----
// A bf16 [M, AS]; WT planes swizzled [128][128]; output bf16 hi-only.
template <int NKC, int AS>
__global__ __launch_bounds__(256) void gemm_mfma_kernel(const unsigned short* __restrict__ A,
                                                        const unsigned short* __restrict__ WT,
                                                        const float* __restrict__ bias,
                                                        unsigned short* __restrict__ act, int M) {
    __shared__ unsigned short lds[2 * 128 * 128];
    const int tid = threadIdx.x;
    {
        const unsigned* s = reinterpret_cast<const unsigned*>(WT);
        unsigned* d = reinterpret_cast<unsigned*>(lds);
#pragma unroll
        for (int i = 0; i < 64; ++i) d[tid + 256 * i] = s[tid + 256 * i];
    }
    __syncthreads();

    const int w = tid >> 6, lane = tid & 63;
    const int m = lane & 15, kb = lane >> 4;
    const char* ldsHiB = reinterpret_cast<const char*>(lds);
    const char* ldsLoB = ldsHiB + 128 * 256;

    float bcol[8];
#pragma unroll
    for (int ct = 0; ct < 8; ++ct) bcol[ct] = bias[ct * 16 + m];

    const int RT = 4;
    for (int rt = 0; rt < RT; ++rt) {
        int row0 = (blockIdx.x * RT + rt) * 64;
        if (row0 >= M) return;
        int arow = row0 + w * 16 + m;

        bf16x8 ah[NKC];
#pragma unroll
        for (int kc = 0; kc < NKC; ++kc)
            ah[kc] = *reinterpret_cast<const bf16x8*>(A + (size_t)arow * AS + kc * 32 + kb * 8);

        f32x4 acc[8];
#pragma unroll
        for (int ct = 0; ct < 8; ++ct)
#pragma unroll
            for (int r = 0; r < 4; ++r) acc[ct][r] = 0.0f;

#pragma unroll
        for (int ct = 0; ct < 8; ++ct) {
            int n = ct * 16 + m;
            int swz = (n & 7) << 4;
            int rowb = n * 256;
#pragma unroll
            for (int kc = 0; kc < NKC; ++kc) {
                int bb = rowb + ((kc * 64 + kb * 16) ^ swz);
                bf16x8 bh = *reinterpret_cast<const bf16x8*>(ldsHiB + bb);
                bf16x8 bl = *reinterpret_cast<const bf16x8*>(ldsLoB + bb);
                acc[ct] = __builtin_amdgcn_mfma_f32_16x16x32_bf16(ah[kc], bh, acc[ct], 0, 0, 0);
                acc[ct] = __builtin_amdgcn_mfma_f32_16x16x32_bf16(ah[kc], bl, acc[ct], 0, 0, 0);
            }
        }

        // C/D: col = ct*16 + (lane&15), row = (lane>>4)*4 + r   [m89]
        unsigned short* ap = act + (size_t)(row0 + w * 16) * 128;
#pragma unroll
        for (int ct = 0; ct < 8; ++ct)
#pragma unroll
            for (int r = 0; r < 4; ++r) {
                float v = fmaxf(acc[ct][r] + bcol[ct], 0.0f);
                ap[(size_t)(kb * 4 + r) * 128 + ct * 16 + m] = bf16_rne(v);
            }
    }
}

// fp32 VALU GEMM for the small FF head
template <bool RELU_A, bool EPI>
__global__ __launch_bounds__(256) void gemm_kernel(const float* __restrict__ A,
                                                   const float* __restrict__ B,
                                                   const float* __restrict__ bias,
                                                   float* __restrict__ C,
                                                   int M, int N, int K) {
    const int BM = 64, BN = 64, BK = 16;
    __shared__ float As[BK][BM + 4];
    __shared__ float Bs[BK][BN + 4];

    const int tid = threadIdx.x;
    const int bm = blockIdx.x * BM;
    const int bn = blockIdx.y * BN;
    const int tx = tid & 15;
    const int ty = tid >> 4;

    const int arow = tid >> 2;
    const int acol = (tid & 3) * 4;
    const int brow = tid >> 4;
    const int bcol = (tid & 15) * 4;

    float acc[4][4] = {};

    for (int k0 = 0; k0 < K; k0 += BK) {
        {
            const float* ap = A + (size_t)(bm + arow) * K;
#pragma unroll
            for (int j = 0; j < 4; ++j) {
                int kk = k0 + acol + j;
                float v = (kk < K) ? ap[kk] : 0.0f;
                if (RELU_A) v = fmaxf(v, 0.0f);
                As[acol + j][arow] = v;
            }
        }
        {
            int kk = k0 + brow;
            float4 v = make_float4(0.f, 0.f, 0.f, 0.f);
            if (kk < K) v = *reinterpret_cast<const float4*>(B + (size_t)kk * N + bn + bcol);
            *reinterpret_cast<float4*>(&Bs[brow][bcol]) = v;
        }
        __syncthreads();
#pragma unroll
        for (int k = 0; k < BK; ++k) {
            float4 a4 = *reinterpret_cast<const float4*>(&As[k][ty * 4]);
            float4 b4 = *reinterpret_cast<const float4*>(&Bs[k][tx * 4]);
            float av[4] = {a4.x, a4.y, a4.z, a4.w};
            float bv[4] = {b4.x, b4.y, b4.z, b4.w};
#pragma unroll
            for (int i = 0; i < 4; ++i)
#pragma unroll
                for (int j = 0; j < 4; ++j)
                    acc[i][j] = fmaf(av[i], bv[j], acc[i][j]);
        }
        __syncthreads();
    }

    const int crow0 = bm + ty * 4;
    const int ccol0 = bn + tx * 4;
    float4 bv = make_float4(0.f, 0.f, 0.f, 0.f);
    if (EPI) bv = *reinterpret_cast<const float4*>(bias + ccol0);
#pragma unroll
    for (int i = 0; i < 4; ++i) {
        float4 v = make_float4(acc[i][0], acc[i][1], acc[i][2], acc[i][3]);
        if (EPI) {
            v.x = fmaxf(v.x + bv.x, 0.f);
            v.y = fmaxf(v.y + bv.y, 0.f);
            v.z = fmaxf(v.z + bv.z, 0.f);
            v.w = fmaxf(v.w + bv.w, 0.f);
        }
        *reinterpret_cast<float4*>(C + (size_t)(crow0 + i) * N + ccol0) = v;
    }
}

// batch sorted: pre-reduce runs of 8 nodes, flush on boundary. reads bf16 act.
__global__ __launch_bounds__(256) void pool_kernel(const unsigned short* __restrict__ act,
                                                   const int* __restrict__ batch,
                                                   int* __restrict__ pooled, int n) {
    int t = blockIdx.x * blockDim.x + threadIdx.x;
    int d = t & 127;
    int n0 = (t >> 7) * 8;
    if (n0 >= n) return;
    int cur = batch[n0];
    float m = fmaxf(bf16_to_f(act[(size_t)n0 * 128 + d]), 0.f);
    for (int i = 1; i < 8 && (n0 + i) < n; ++i) {
        int b = batch[n0 + i];
        float v = fmaxf(bf16_to_f(act[(size_t)(n0 + i) * 128 + d]), 0.f);
        if (b == cur) {
            m = fmaxf(m, v);
        } else {
            atomicMax(&pooled[cur * 128 + d], __float_as_int(m));
            cur = b;
            m = v;
        }
    }
    atomicMax(&pooled[cur * 128 + d], __float_as_int(m));
}

extern "C" void kernel_launch(void* const* d_in, const int* in_sizes, int n_in,
                              void* d_out, int out_size, void* d_ws, size_t ws_size,
                              hipStream_t stream) {
    const float* x    = (const float*)d_in[0];
    const int*   edge = (const int*)d_in[1];
    const int*   batch= (const int*)d_in[2];
    const float* gW0  = (const float*)d_in[4];
    const float* gb0  = (const float*)d_in[5];
    const float* gW1  = (const float*)d_in[6];
    const float* gb1  = (const float*)d_in[7];
    const float* gW2  = (const float*)d_in[8];
    const float* gb2  = (const float*)d_in[9];
    const float* fW0  = (const float*)d_in[10];
    const float* fb0  = (const float*)d_in[11];
    const float* fW1  = (const float*)d_in[12];
    const float* fb1  = (const float*)d_in[13];
    float* out = (float*)d_out;

    unsigned short* actB  = (unsigned short*)d_ws;            // NN*128 bf16 (aliases xbf NN*96)
    unsigned short* aggHi = actB + (size_t)NN * 128;          // NN*128 bf16
    float* disq   = (float*)(aggHi + (size_t)NN * 128);       // NN
    float* pooled = disq + NN;                                // NG*128
    float* ffh    = pooled + (size_t)NG * 128;                // NG*256
    int*   deg    = (int*)(ffh + (size_t)NG * 256);           // NN
    int*   rowptr = deg + NN;                                 // NN
    int2*  csr_ent = (int2*)(rowptr + NN);                    // NE
    unsigned short* wt0 = (unsigned short*)(csr_ent + NE);    // 2*128*128 each
    unsigned short* wt1 = wt0 + 2 * 128 * 128;
    unsigned short* wt2 = wt1 + 2 * 128 * 128;
    int* partials = (int*)(wt2 + 2 * 128 * 128);              // ~200 ints
    int* cnt = (int*)pooled;                                  // dead before pool init
    unsigned short* xbf = actB;                               // [NN,96] hi-only; dead after gather0

    const int* src = edge;
    const int* dst = edge + NE;

    // ---- degree + disq + CSR build + weight prep + x convert ----
    fill_int_kernel<<<cdiv(NN, 256), 256, 0, stream>>>(deg, 0, NN);
    fill_int_kernel<<<cdiv(NN, 256), 256, 0, stream>>>(cnt, 0, NN);
    hist_kernel<<<cdiv(NE, 256), 256, 0, stream>>>(dst, deg, NE);
    disq_kernel<<<cdiv(NN, 256), 256, 0, stream>>>(deg, disq, NN);
    int nsb = cdiv(NN, SCAN_BE);
    scan_a_kernel<<<nsb, SCAN_TPB, 0, stream>>>(deg, rowptr, partials, NN);
    scan_b_kernel<<<1, 64, 0, stream>>>(partials, nsb);
    scan_c_kernel<<<cdiv(NN, 256), 256, 0, stream>>>(rowptr, partials, NN);
    csr_fill_kernel<<<cdiv(NE, 256), 256, 0, stream>>>(src, dst, rowptr, cnt, disq,
                                                       csr_ent, NE);
    prep_w_kernel<<<64, 256, 0, stream>>>(gW0, 78, wt0, wt0 + 128 * 128);
    prep_w_kernel<<<64, 256, 0, stream>>>(gW1, 128, wt1, wt1 + 128 * 128);
    prep_w_kernel<<<64, 256, 0, stream>>>(gW2, 128, wt2, wt2 + 128 * 128);
    xconv_kernel<<<cdiv(NN * 96, 256), 256, 0, stream>>>(x, xbf);

    const int gemm_blocks = cdiv(NN / 64, 4);
    const int gather_blocks = cdiv(NN * 16, 256);

    // ---- layer 0: agg = A_hat x ; act = relu(agg@W0 + b0) ----
    gather_kernel<96><<<gather_blocks, 256, 0, stream>>>(xbf, rowptr, deg, csr_ent, disq,
                                                         aggHi, NN);
    gemm_mfma_kernel<3, 96><<<gemm_blocks, 256, 0, stream>>>(aggHi, wt0, gb0, actB, NN);
    // ---- layer 1 ----
    gather_kernel<128><<<gather_blocks, 256, 0, stream>>>(actB, rowptr, deg, csr_ent, disq,
                                                          aggHi, NN);
    gemm_mfma_kernel<4, 128><<<gemm_blocks, 256, 0, stream>>>(aggHi, wt1, gb1, actB, NN);
    // ---- layer 2 ----
    gather_kernel<128><<<gather_blocks, 256, 0, stream>>>(actB, rowptr, deg, csr_ent, disq,
                                                          aggHi, NN);
    gemm_mfma_kernel<4, 128><<<gemm_blocks, 256, 0, stream>>>(aggHi, wt2, gb2, actB, NN);

    // ---- global max pool ----
    fill_kernel<<<cdiv(NG * 128, 256), 256, 0, stream>>>(pooled, 0.0f, NG * 128);
    pool_kernel<<<cdiv(cdiv(NN, 8) * 128, 256), 256, 0, stream>>>(actB, batch, (int*)pooled, NN);

    // ---- FF head (small, fp32 VALU) ----
    gemm_kernel<false, true><<<dim3(NG / 64, 4), 256, 0, stream>>>(pooled, fW0, fb0, ffh, NG, 256, 128);
    gemm_kernel<false, true><<<dim3(NG / 64, 2), 256, 0, stream>>>(ffh, fW1, fb1, out, NG, 128, 256);
}

// Round 8
// 597.138 us; speedup vs baseline: 8.5445x; 1.0509x over previous
//
#include <hip/hip_runtime.h>

#define NN 400000
#define NE 800000
#define NG 16384

typedef short bf16x8 __attribute__((ext_vector_type(8)));
typedef float f32x4 __attribute__((ext_vector_type(4)));
typedef unsigned short u16x8 __attribute__((ext_vector_type(8)));

static inline int cdiv(int a, int b) { return (a + b - 1) / b; }

__device__ inline unsigned short bf16_rne(float v) {
    unsigned u = __float_as_uint(v);
    unsigned r = u + 0x7FFFu + ((u >> 16) & 1u);
    return (unsigned short)(r >> 16);
}
__device__ inline float bf16_to_f(unsigned short h) {
    return __uint_as_float(((unsigned)h) << 16);
}
__device__ inline void split2(float v, unsigned short& hi, unsigned short& lo) {
    hi = bf16_rne(v);
    lo = bf16_rne(v - bf16_to_f(hi));
}

__global__ __launch_bounds__(256) void fill_kernel(float* __restrict__ p, float v, int n) {
    int i = blockIdx.x * blockDim.x + threadIdx.x;
    if (i < n) p[i] = v;
}

__global__ __launch_bounds__(256) void fill_int_kernel(int* __restrict__ p, int v, int n) {
    int i = blockIdx.x * blockDim.x + threadIdx.x;
    if (i < n) p[i] = v;
}

__global__ __launch_bounds__(256) void hist_kernel(const int* __restrict__ dst,
                                                   int* __restrict__ deg, int E) {
    int e = blockIdx.x * blockDim.x + threadIdx.x;
    if (e < E) atomicAdd(&deg[dst[e]], 1);
}

__global__ __launch_bounds__(256) void disq_kernel(const int* __restrict__ deg,
                                                   float* __restrict__ disq, int n) {
    int i = blockIdx.x * blockDim.x + threadIdx.x;
    if (i < n) disq[i] = rsqrtf(1.0f + (float)deg[i]);
}

// ---- 3-pass exclusive scan ----
#define SCAN_TPB 256
#define SCAN_EPT 8
#define SCAN_BE (SCAN_TPB * SCAN_EPT)

__global__ __launch_bounds__(SCAN_TPB) void scan_a_kernel(const int* __restrict__ in,
                                                          int* __restrict__ out,
                                                          int* __restrict__ partials, int n) {
    __shared__ int sums[SCAN_TPB];
    const int tid = threadIdx.x;
    int base = blockIdx.x * SCAN_BE + tid * SCAN_EPT;
    int v[SCAN_EPT];
    int s = 0;
#pragma unroll
    for (int i = 0; i < SCAN_EPT; ++i) {
        int idx = base + i;
        int x = (idx < n) ? in[idx] : 0;
        v[i] = s;
        s += x;
    }
    sums[tid] = s;
    __syncthreads();
    for (int off = 1; off < SCAN_TPB; off <<= 1) {
        int t = (tid >= off) ? sums[tid - off] : 0;
        __syncthreads();
        sums[tid] += t;
        __syncthreads();
    }
    int toff = (tid == 0) ? 0 : sums[tid - 1];
#pragma unroll
    for (int i = 0; i < SCAN_EPT; ++i) {
        int idx = base + i;
        if (idx < n) out[idx] = toff + v[i];
    }
    if (tid == SCAN_TPB - 1) partials[blockIdx.x] = sums[SCAN_TPB - 1];
}

__global__ void scan_b_kernel(int* __restrict__ partials, int nb) {
    if (blockIdx.x == 0 && threadIdx.x == 0) {
        int s = 0;
        for (int i = 0; i < nb; ++i) { int x = partials[i]; partials[i] = s; s += x; }
    }
}

__global__ __launch_bounds__(256) void scan_c_kernel(int* __restrict__ out,
                                                     const int* __restrict__ partials, int n) {
    int idx = blockIdx.x * blockDim.x + threadIdx.x;
    if (idx < n) out[idx] += partials[idx / SCAN_BE];
}

// ---- CSR fill: entry = {src, norm_bits} packed ----
__global__ __launch_bounds__(256) void csr_fill_kernel(const int* __restrict__ src,
                                                       const int* __restrict__ dst,
                                                       const int* __restrict__ rowptr,
                                                       int* __restrict__ cnt,
                                                       const float* __restrict__ disq,
                                                       int2* __restrict__ csr_ent, int E) {
    int e = blockIdx.x * blockDim.x + threadIdx.x;
    if (e >= E) return;
    int d = dst[e], s = src[e];
    int pos = rowptr[d] + atomicAdd(&cnt[d], 1);
    csr_ent[pos] = make_int2(s, __float_as_int(disq[s] * disq[d]));
}

// ---- weight prep: 128x128 slice (k0.., n0..) of W[Ktot][Ntot] fp32
//      -> transposed, split, XOR-swizzled planes ----
__global__ __launch_bounds__(256) void prep_w_kernel(const float* __restrict__ W,
                                                     int Ktot, int Ntot, int k0, int n0,
                                                     unsigned short* __restrict__ planeHi,
                                                     unsigned short* __restrict__ planeLo) {
    int i = blockIdx.x * blockDim.x + threadIdx.x;
    if (i >= 128 * 128) return;
    int n = i >> 7, k = i & 127;
    int gk = k0 + k, gn = n0 + n;
    float v = (gk < Ktot && gn < Ntot) ? W[(size_t)gk * Ntot + gn] : 0.0f;
    unsigned short hi, lo;
    split2(v, hi, lo);
    int elem = (n * 256 + ((2 * k) ^ ((n & 7) << 4))) >> 1;
    planeHi[elem] = hi;
    planeLo[elem] = lo;
}

// ---- x convert: [NN][78] fp32 -> bf16 hi-only [NN][96] (zero pad) ----
// int32 math, 4 elems/thread, ushort4 stores.
__global__ __launch_bounds__(256) void xconv_kernel(const float* __restrict__ x,
                                                    unsigned short* __restrict__ xbf) {
    int t = blockIdx.x * blockDim.x + threadIdx.x;
    if (t >= NN * 24) return;
    int node = t / 24;              // int32 magic-mul
    int q = (t - node * 24) * 4;    // 0,4,...,92
    const float* xp = x + (size_t)node * 78;
    ushort4 o;
    o.x = bf16_rne((q + 0 < 78) ? xp[q + 0] : 0.0f);
    o.y = bf16_rne((q + 1 < 78) ? xp[q + 1] : 0.0f);
    o.z = bf16_rne((q + 2 < 78) ? xp[q + 2] : 0.0f);
    o.w = bf16_rne((q + 3 < 78) ? xp[q + 3] : 0.0f);
    *reinterpret_cast<ushort4*>(xbf + (size_t)node * 96 + q) = o;
}

// ---- fp32 -> bf16 vector convert ----
__global__ __launch_bounds__(256) void f2bf_kernel(const float* __restrict__ in,
                                                   unsigned short* __restrict__ o, int n4) {
    int i = blockIdx.x * blockDim.x + threadIdx.x;
    if (i >= n4) return;
    float4 v = *reinterpret_cast<const float4*>(in + i * 4);
    ushort4 u;
    u.x = bf16_rne(v.x); u.y = bf16_rne(v.y); u.z = bf16_rne(v.z); u.w = bf16_rne(v.w);
    *reinterpret_cast<ushort4*>(o + i * 4) = u;
}

// ---- CSR gather over bf16 activations -> bf16 hi-only agg ----
// 16 lanes/node, ushort8 (16B) per lane -> 4 independent node chains per wave.
template <int STRIDE>
__global__ __launch_bounds__(256) void gather_kernel(const unsigned short* __restrict__ act,
                                                     const int* __restrict__ rowptr,
                                                     const int* __restrict__ deg,
                                                     const int2* __restrict__ csr_ent,
                                                     const float* __restrict__ disq,
                                                     unsigned short* __restrict__ aggHi, int n) {
    int t = blockIdx.x * blockDim.x + threadIdx.x;
    if (t >= n * 16) return;
    int node = t >> 4, q = (t & 15) * 8;
    const bool live = q < STRIDE;
    const int qc = live ? q : 0;
    int beg = rowptr[node];
    int d = deg[node];
    float si = disq[node];
    float s2 = si * si;
    u16x8 su = *reinterpret_cast<const u16x8*>(act + (size_t)node * STRIDE + qc);
    float acc[8];
#pragma unroll
    for (int i = 0; i < 8; ++i) acc[i] = bf16_to_f(su[i]) * s2;
    if (d > 0) {
        int lim = d - 1;
        int2 e[6];
#pragma unroll
        for (int j = 0; j < 6; ++j) e[j] = csr_ent[beg + (j < lim ? j : lim)];
        u16x8 u[6];
        float nr[6];
#pragma unroll
        for (int j = 0; j < 6; ++j) {
            u[j] = *reinterpret_cast<const u16x8*>(act + (size_t)e[j].x * STRIDE + qc);
            nr[j] = (j < d) ? __int_as_float(e[j].y) : 0.0f;
        }
#pragma unroll
        for (int j = 0; j < 6; ++j)
#pragma unroll
            for (int i = 0; i < 8; ++i) acc[i] = fmaf(bf16_to_f(u[j][i]), nr[j], acc[i]);
        for (int j = 6; j < d; ++j) {
            int2 ee = csr_ent[beg + j];
            float nn = __int_as_float(ee.y);
            u16x8 uu = *reinterpret_cast<const u16x8*>(act + (size_t)ee.x * STRIDE + qc);
#pragma unroll
            for (int i = 0; i < 8; ++i) acc[i] = fmaf(bf16_to_f(uu[i]), nn, acc[i]);
        }
    }
    if (live) {
        u16x8 h8;
#pragma unroll
        for (int i = 0; i < 8; ++i) h8[i] = bf16_rne(acc[i]);
        *reinterpret_cast<u16x8*>(aggHi + (size_t)node * STRIDE + q) = h8;
    }
}

// ---- bf16 MFMA GEMM, split weights (Whi+Wlo), 3 epilogue modes ----
// MODE 0: bf16 out = relu(acc + bias), row stride ostride, col offset ocol
// MODE 1: fp32 partial out (no bias/relu), stride 128
// MODE 2: fp32 out = relu(acc + partial + bias), stride 128
template <int NKC, int AS, int MODE>
__global__ __launch_bounds__(256) void gemm_mfma_kernel(const unsigned short* __restrict__ A,
                                                        const unsigned short* __restrict__ WT,
                                                        const float* __restrict__ bias,
                                                        unsigned short* __restrict__ actout,
                                                        float* __restrict__ f32out,
                                                        const float* __restrict__ partial,
                                                        int M, int a_k0, int ostride, int ocol) {
    __shared__ unsigned short lds[2 * 128 * 128];
    const int tid = threadIdx.x;
    {
        const unsigned* s = reinterpret_cast<const unsigned*>(WT);
        unsigned* d = reinterpret_cast<unsigned*>(lds);
#pragma unroll
        for (int i = 0; i < 64; ++i) d[tid + 256 * i] = s[tid + 256 * i];
    }
    __syncthreads();

    const int w = tid >> 6, lane = tid & 63;
    const int m = lane & 15, kb = lane >> 4;
    const char* ldsHiB = reinterpret_cast<const char*>(lds);
    const char* ldsLoB = ldsHiB + 128 * 256;

    float bcol[8];
    if (MODE != 1) {
#pragma unroll
        for (int ct = 0; ct < 8; ++ct) bcol[ct] = bias[ct * 16 + m];
    }

    const int RT = 4;
    for (int rt = 0; rt < RT; ++rt) {
        int row0 = (blockIdx.x * RT + rt) * 64;
        if (row0 >= M) return;
        int arow = row0 + w * 16 + m;

        bf16x8 ah[NKC];
#pragma unroll
        for (int kc = 0; kc < NKC; ++kc)
            ah[kc] = *reinterpret_cast<const bf16x8*>(A + (size_t)arow * AS + a_k0 + kc * 32 + kb * 8);

        f32x4 acc[8];
#pragma unroll
        for (int ct = 0; ct < 8; ++ct)
#pragma unroll
            for (int r = 0; r < 4; ++r) acc[ct][r] = 0.0f;

#pragma unroll
        for (int ct = 0; ct < 8; ++ct) {
            int n = ct * 16 + m;
            int swz = (n & 7) << 4;
            int rowb = n * 256;
#pragma unroll
            for (int kc = 0; kc < NKC; ++kc) {
                int bb = rowb + ((kc * 64 + kb * 16) ^ swz);
                bf16x8 bh = *reinterpret_cast<const bf16x8*>(ldsHiB + bb);
                bf16x8 bl = *reinterpret_cast<const bf16x8*>(ldsLoB + bb);
                acc[ct] = __builtin_amdgcn_mfma_f32_16x16x32_bf16(ah[kc], bh, acc[ct], 0, 0, 0);
                acc[ct] = __builtin_amdgcn_mfma_f32_16x16x32_bf16(ah[kc], bl, acc[ct], 0, 0, 0);
            }
        }

        // C/D: col = ct*16 + (lane&15), row = (lane>>4)*4 + r   [m89]
        if (MODE == 0) {
            unsigned short* ap = actout + (size_t)(row0 + w * 16) * ostride + ocol;
#pragma unroll
            for (int ct = 0; ct < 8; ++ct)
#pragma unroll
                for (int r = 0; r < 4; ++r) {
                    float v = fmaxf(acc[ct][r] + bcol[ct], 0.0f);
                    ap[(size_t)(kb * 4 + r) * ostride + ct * 16 + m] = bf16_rne(v);
                }
        } else if (MODE == 1) {
            float* fp = f32out + (size_t)(row0 + w * 16) * 128;
#pragma unroll
            for (int ct = 0; ct < 8; ++ct)
#pragma unroll
                for (int r = 0; r < 4; ++r)
                    fp[(size_t)(kb * 4 + r) * 128 + ct * 16 + m] = acc[ct][r];
        } else {
            const float* pp = partial + (size_t)(row0 + w * 16) * 128;
            float* fp = f32out + (size_t)(row0 + w * 16) * 128;
#pragma unroll
            for (int ct = 0; ct < 8; ++ct)
#pragma unroll
                for (int r = 0; r < 4; ++r) {
                    size_t idx = (size_t)(kb * 4 + r) * 128 + ct * 16 + m;
                    float v = fmaxf(acc[ct][r] + pp[idx] + bcol[ct], 0.0f);
                    fp[idx] = v;
                }
        }
    }
}

// batch sorted: pre-reduce runs of 8 nodes, flush on boundary. reads bf16 act.
__global__ __launch_bounds__(256) void pool_kernel(const unsigned short* __restrict__ act,
                                                   const int* __restrict__ batch,
                                                   int* __restrict__ pooled, int n) {
    int t = blockIdx.x * blockDim.x + threadIdx.x;
    int d = t & 127;
    int n0 = (t >> 7) * 8;
    if (n0 >= n) return;
    int cur = batch[n0];
    float m = fmaxf(bf16_to_f(act[(size_t)n0 * 128 + d]), 0.f);
    for (int i = 1; i < 8 && (n0 + i) < n; ++i) {
        int b = batch[n0 + i];
        float v = fmaxf(bf16_to_f(act[(size_t)(n0 + i) * 128 + d]), 0.f);
        if (b == cur) {
            m = fmaxf(m, v);
        } else {
            atomicMax(&pooled[cur * 128 + d], __float_as_int(m));
            cur = b;
            m = v;
        }
    }
    atomicMax(&pooled[cur * 128 + d], __float_as_int(m));
}

extern "C" void kernel_launch(void* const* d_in, const int* in_sizes, int n_in,
                              void* d_out, int out_size, void* d_ws, size_t ws_size,
                              hipStream_t stream) {
    const float* x    = (const float*)d_in[0];
    const int*   edge = (const int*)d_in[1];
    const int*   batch= (const int*)d_in[2];
    const float* gW0  = (const float*)d_in[4];
    const float* gb0  = (const float*)d_in[5];
    const float* gW1  = (const float*)d_in[6];
    const float* gb1  = (const float*)d_in[7];
    const float* gW2  = (const float*)d_in[8];
    const float* gb2  = (const float*)d_in[9];
    const float* fW0  = (const float*)d_in[10];
    const float* fb0  = (const float*)d_in[11];
    const float* fW1  = (const float*)d_in[12];
    const float* fb1  = (const float*)d_in[13];
    float* out = (float*)d_out;

    unsigned short* actB  = (unsigned short*)d_ws;            // NN*128 bf16 (aliases xbf NN*96)
    unsigned short* aggHi = actB + (size_t)NN * 128;          // NN*128 bf16
    float* disq   = (float*)(aggHi + (size_t)NN * 128);       // NN f32
    float* pooled = disq + NN;                                // NG*128 f32 (also FF1 partial)
    unsigned short* pooledbf = (unsigned short*)(pooled + (size_t)NG * 128);  // NG*128
    unsigned short* ffhbf    = pooledbf + (size_t)NG * 128;   // NG*256
    int*   deg    = (int*)(ffhbf + (size_t)NG * 256);         // NN
    int*   rowptr = deg + NN;                                 // NN
    int2*  csr_ent = (int2*)(rowptr + NN);                    // NE
    unsigned short* wt0  = (unsigned short*)(csr_ent + NE);   // 2*128*128 each
    unsigned short* wt1  = wt0 + 2 * 128 * 128;
    unsigned short* wt2  = wt1 + 2 * 128 * 128;
    unsigned short* wtF0a = wt2 + 2 * 128 * 128;
    unsigned short* wtF0b = wtF0a + 2 * 128 * 128;
    unsigned short* wtF1a = wtF0b + 2 * 128 * 128;
    unsigned short* wtF1b = wtF1a + 2 * 128 * 128;
    int* partials = (int*)(wtF1b + 2 * 128 * 128);            // ~200 ints
    int* cnt = (int*)pooled;                                  // dead before pool init
    unsigned short* xbf = actB;                               // [NN,96]; dead after gather0

    const int* src = edge;
    const int* dst = edge + NE;

    // ---- degree + disq + CSR build + weight prep + x convert ----
    fill_int_kernel<<<cdiv(NN, 256), 256, 0, stream>>>(deg, 0, NN);
    fill_int_kernel<<<cdiv(NN, 256), 256, 0, stream>>>(cnt, 0, NN);
    hist_kernel<<<cdiv(NE, 256), 256, 0, stream>>>(dst, deg, NE);
    disq_kernel<<<cdiv(NN, 256), 256, 0, stream>>>(deg, disq, NN);
    int nsb = cdiv(NN, SCAN_BE);
    scan_a_kernel<<<nsb, SCAN_TPB, 0, stream>>>(deg, rowptr, partials, NN);
    scan_b_kernel<<<1, 64, 0, stream>>>(partials, nsb);
    scan_c_kernel<<<cdiv(NN, 256), 256, 0, stream>>>(rowptr, partials, NN);
    csr_fill_kernel<<<cdiv(NE, 256), 256, 0, stream>>>(src, dst, rowptr, cnt, disq,
                                                       csr_ent, NE);
    prep_w_kernel<<<64, 256, 0, stream>>>(gW0, 78, 128, 0, 0, wt0, wt0 + 128 * 128);
    prep_w_kernel<<<64, 256, 0, stream>>>(gW1, 128, 128, 0, 0, wt1, wt1 + 128 * 128);
    prep_w_kernel<<<64, 256, 0, stream>>>(gW2, 128, 128, 0, 0, wt2, wt2 + 128 * 128);
    prep_w_kernel<<<64, 256, 0, stream>>>(fW0, 128, 256, 0, 0,   wtF0a, wtF0a + 128 * 128);
    prep_w_kernel<<<64, 256, 0, stream>>>(fW0, 128, 256, 0, 128, wtF0b, wtF0b + 128 * 128);
    prep_w_kernel<<<64, 256, 0, stream>>>(fW1, 256, 128, 0, 0,   wtF1a, wtF1a + 128 * 128);
    prep_w_kernel<<<64, 256, 0, stream>>>(fW1, 256, 128, 128, 0, wtF1b, wtF1b + 128 * 128);
    xconv_kernel<<<cdiv(NN * 24, 256), 256, 0, stream>>>(x, xbf);

    const int gemm_blocks = cdiv(NN / 64, 4);
    const int gather_blocks = cdiv(NN * 16, 256);
    const int ff_blocks = NG / 256;

    // ---- layer 0: agg = A_hat x ; act = relu(agg@W0 + b0) ----
    gather_kernel<96><<<gather_blocks, 256, 0, stream>>>(xbf, rowptr, deg, csr_ent, disq,
                                                         aggHi, NN);
    gemm_mfma_kernel<3, 96, 0><<<gemm_blocks, 256, 0, stream>>>(
        aggHi, wt0, gb0, actB, nullptr, nullptr, NN, 0, 128, 0);
    // ---- layer 1 ----
    gather_kernel<128><<<gather_blocks, 256, 0, stream>>>(actB, rowptr, deg, csr_ent, disq,
                                                          aggHi, NN);
    gemm_mfma_kernel<4, 128, 0><<<gemm_blocks, 256, 0, stream>>>(
        aggHi, wt1, gb1, actB, nullptr, nullptr, NN, 0, 128, 0);
    // ---- layer 2 ----
    gather_kernel<128><<<gather_blocks, 256, 0, stream>>>(actB, rowptr, deg, csr_ent, disq,
                                                          aggHi, NN);
    gemm_mfma_kernel<4, 128, 0><<<gemm_blocks, 256, 0, stream>>>(
        aggHi, wt2, gb2, actB, nullptr, nullptr, NN, 0, 128, 0);

    // ---- global max pool ----
    fill_kernel<<<cdiv(NG * 128, 256), 256, 0, stream>>>(pooled, 0.0f, NG * 128);
    pool_kernel<<<cdiv(cdiv(NN, 8) * 128, 256), 256, 0, stream>>>(actB, batch, (int*)pooled, NN);
    f2bf_kernel<<<cdiv(NG * 32, 256), 256, 0, stream>>>(pooled, pooledbf, NG * 32);

    // ---- FF head (MFMA) ----
    // FF0: ffh = relu(pooled @ fW0 + fb0), N=256 via two col-blocks
    gemm_mfma_kernel<4, 128, 0><<<ff_blocks, 256, 0, stream>>>(
        pooledbf, wtF0a, fb0, ffhbf, nullptr, nullptr, NG, 0, 256, 0);
    gemm_mfma_kernel<4, 128, 0><<<ff_blocks, 256, 0, stream>>>(
        pooledbf, wtF0b, fb0 + 128, ffhbf, nullptr, nullptr, NG, 0, 256, 128);
    // FF1: out = relu(ffh @ fW1 + fb1), K=256 via split-K (partial in 'pooled')
    gemm_mfma_kernel<4, 256, 1><<<ff_blocks, 256, 0, stream>>>(
        ffhbf, wtF1a, nullptr, nullptr, pooled, nullptr, NG, 0, 128, 0);
    gemm_mfma_kernel<4, 256, 2><<<ff_blocks, 256, 0, stream>>>(
        ffhbf, wtF1b, fb1, nullptr, out, pooled, NG, 128, 128, 0);
}